// Round 4
// baseline (816.301 us; speedup 1.0000x reference)
//
#include <hip/hip_runtime.h>

// Problem constants
constexpr int HW  = 6400;   // 80*80
constexpr int WW  = 80;

__device__ __forceinline__ float sigmoidf_(float x) { return 1.f / (1.f + __expf(-x)); }
__device__ __forceinline__ float siluf_(float y) { return y / (1.f + __expf(-y)); }

// ---------------------------------------------------------------------------
// k0: weight pre-transposes
//   WrT[cs][m]              (512 x 128)      from reduce_w[m][cs]
//   WoT[(c*9+q)*32 + o]     (1152 x 32pad)   from off_w[o][c][q]   (o<27)
//   Wd [(k*128+c)*256 + o]  (9*128 x 256)    from dcn_w[o][c][k]
// ---------------------------------------------------------------------------
__global__ __launch_bounds__(256) void k0_prep(
    const float* __restrict__ rw, const float* __restrict__ ow,
    const float* __restrict__ dw,
    float* __restrict__ WrT, float* __restrict__ WoT, float* __restrict__ Wd)
{
    const int i = blockIdx.x * 256 + threadIdx.x;
    if (i < 65536) {                       // 512*128
        const int cs = i >> 7, m = i & 127;
        WrT[i] = rw[m * 512 + cs];
    }
    const int j = i - 65536;
    if (j >= 0 && j < 31104) {             // 1152*27
        const int r = j / 27, o = j % 27;
        WoT[r * 32 + o] = ow[o * 1152 + r];
    }
    const int l = j - 31104;
    if (l >= 0 && l < 294912) {            // 9*128*256
        const int o = l & 255;
        const int rem = l >> 8;
        const int c = rem & 127, k = rem >> 7;
        Wd[(k * 128 + c) * 256 + o] = dw[o * 1152 + c * 9 + k];
    }
}

// ---------------------------------------------------------------------------
// k1: space-to-depth + 1x1 conv (512->128) + BN + SiLU  ->  xm (8,128,80,80)
// block: 256 thr = 4 waves; wave wv owns channels [wv*32, wv*32+32), lane = px
// ---------------------------------------------------------------------------
__global__ __launch_bounds__(256) void k1_reduce(
    const float* __restrict__ x, const float* __restrict__ WrT,
    const float* __restrict__ g, const float* __restrict__ be,
    const float* __restrict__ mu, const float* __restrict__ va,
    float* __restrict__ xm)
{
    const int t = threadIdx.x;
    const int lane = t & 63;
    const int m0 = __builtin_amdgcn_readfirstlane((t >> 6) * 32);
    const int pi = blockIdx.x * 64 + lane;          // 0..51199
    const int b = pi / HW;
    const int hw = pi % HW;
    const int h = hw / WW, w = hw % WW;

    const float* xb = x + (size_t)b * 128 * 25600 + (2 * h) * 160 + 2 * w;

    float acc[32];
#pragma unroll
    for (int i = 0; i < 32; ++i) acc[i] = 0.f;

    for (int cs = 0; cs < 512; ++cs) {
        const int c = cs >> 2, sy = (cs >> 1) & 1, sx = cs & 1;
        const float xv = xb[c * 25600 + sy * 160 + sx];
        const float* wr = WrT + cs * 128 + m0;
#pragma unroll
        for (int i = 0; i < 32; ++i) acc[i] = fmaf(wr[i], xv, acc[i]);
    }

    float* op = xm + (size_t)b * 128 * HW + hw;
#pragma unroll
    for (int i = 0; i < 32; ++i) {
        const int m = m0 + i;
        const float sc = g[m] * rsqrtf(va[m] + 1e-5f);
        const float y = (acc[i] - mu[m]) * sc + be[m];
        op[(size_t)m * HW] = siluf_(y);
    }
}

// ---------------------------------------------------------------------------
// k2: 3x3 conv (128->27) + bias  ->  om (8,27,80,80)
// grid (200,3): blockIdx.y = group of 9 output channels; thread = pixel
// ---------------------------------------------------------------------------
__global__ __launch_bounds__(256) void k2_off(
    const float* __restrict__ xm, const float* __restrict__ WoT,
    const float* __restrict__ obias, float* __restrict__ om)
{
    const int pi = blockIdx.x * 256 + threadIdx.x;  // 0..51199
    const int og = blockIdx.y;                      // 0..2
    const int b = pi / HW;
    const int hw = pi % HW;
    const int h = hw / WW, w = hw % WW;
    const float* xb = xm + (size_t)b * 128 * HW;

    float acc[9];
#pragma unroll
    for (int o = 0; o < 9; ++o) acc[o] = 0.f;

    for (int c = 0; c < 128; ++c) {
        float xq[9];
#pragma unroll
        for (int dy = 0; dy < 3; ++dy)
#pragma unroll
            for (int dx = 0; dx < 3; ++dx) {
                const int y = h + dy - 1, xx = w + dx - 1;
                const bool v = ((unsigned)y < 80u) && ((unsigned)xx < 80u);
                xq[dy * 3 + dx] = v ? xb[c * HW + y * WW + xx] : 0.f;
            }
#pragma unroll
        for (int q = 0; q < 9; ++q) {
            const float* wp = WoT + (c * 9 + q) * 32 + og * 9;
            const float xv = xq[q];
#pragma unroll
            for (int o = 0; o < 9; ++o) acc[o] = fmaf(xv, wp[o], acc[o]);
        }
    }

    float* op = om + (size_t)b * 27 * HW + hw;
#pragma unroll
    for (int o = 0; o < 9; ++o) op[(og * 9 + o) * HW] = acc[o] + obias[og * 9 + o];
}

// ---------------------------------------------------------------------------
// k3: deformable sampling + einsum (bckhw,ock->bohw) + BN + SiLU -> out
// block: 256 thr, 32 pixels.  Per k-tap:
//   sample phase: thread (cg=t>>5, p=t&31) fills S[c][p] (128x32 LDS tile)
//   gemm phase:   thread (o0=t&127, half=t>>7) accumulates 2 o-chans x 16 px
// ---------------------------------------------------------------------------
__global__ __launch_bounds__(256) void k3_dcn(
    const float* __restrict__ xm, const float* __restrict__ om,
    const float* __restrict__ Wd,
    const float* __restrict__ g, const float* __restrict__ be,
    const float* __restrict__ mu, const float* __restrict__ va,
    float* __restrict__ out)
{
    __shared__ __align__(16) float S[128 * 32];

    const int t = threadIdx.x;
    const int p0 = blockIdx.x * 32;

    // gemm role
    const int o0 = t & 127;
    const int half = t >> 7;
    float acc0[16], acc1[16];
#pragma unroll
    for (int i = 0; i < 16; ++i) { acc0[i] = 0.f; acc1[i] = 0.f; }

    // sampling role
    const int sp = t & 31;
    const int cg = t >> 5;
    const int pi = p0 + sp;
    const int b = pi / HW;
    const int hw = pi % HW;
    const int h = hw / WW, w = hw % WW;
    const float* xb = xm + (size_t)b * 128 * HW;
    const float* ob = om + (size_t)b * 27 * HW + hw;

    for (int k = 0; k < 9; ++k) {
        // --- per-pixel sampling geometry (recomputed by each cg group) ---
        const float oy = ob[(2 * k) * HW];
        const float ox = ob[(2 * k + 1) * HW];
        const float mk = sigmoidf_(ob[(18 + k) * HW]);

        float py = (float)(h - 1 + k / 3) + oy;
        float px = (float)(w - 1 + k % 3) + ox;
        py = fminf(fmaxf(py, -1000.f), 1000.f);
        px = fminf(fmaxf(px, -1000.f), 1000.f);
        const float fy = floorf(py), fx = floorf(px);
        const int y0 = (int)fy, x0 = (int)fx;
        const int y1 = y0 + 1, x1 = x0 + 1;
        const float wy = py - fy, wx = px - fx;

        const float vy0 = ((unsigned)y0 < 80u) ? 1.f : 0.f;
        const float vy1 = ((unsigned)y1 < 80u) ? 1.f : 0.f;
        const float vx0 = ((unsigned)x0 < 80u) ? 1.f : 0.f;
        const float vx1 = ((unsigned)x1 < 80u) ? 1.f : 0.f;

        const float w00 = (1.f - wy) * (1.f - wx) * vy0 * vx0 * mk;
        const float w01 = (1.f - wy) * wx * vy0 * vx1 * mk;
        const float w10 = wy * (1.f - wx) * vy1 * vx0 * mk;
        const float w11 = wy * wx * vy1 * vx1 * mk;

        const int cy0 = min(max(y0, 0), 79), cy1 = min(max(y1, 0), 79);
        const int cx0 = min(max(x0, 0), 79), cx1 = min(max(x1, 0), 79);
        const int i00 = cy0 * WW + cx0, i01 = cy0 * WW + cx1;
        const int i10 = cy1 * WW + cx0, i11 = cy1 * WW + cx1;

        __syncthreads();   // previous gemm phase done reading S

        // --- fill S tile: 16 channels per thread ---
#pragma unroll 4
        for (int cc = 0; cc < 16; ++cc) {
            const int c = cg * 16 + cc;
            const float* xc = xb + c * HW;
            const float s = w00 * xc[i00] + w01 * xc[i01] +
                            w10 * xc[i10] + w11 * xc[i11];
            S[c * 32 + sp] = s;
        }

        __syncthreads();

        // --- gemm phase: out[o0], out[o0+128] over 16 pixels ---
        const float* wk = Wd + k * 128 * 256;
        for (int c = 0; c < 128; ++c) {
            const float w0 = wk[c * 256 + o0];
            const float w1 = wk[c * 256 + 128 + o0];
            const float4* s4 = (const float4*)&S[c * 32 + half * 16];
#pragma unroll
            for (int j = 0; j < 4; ++j) {
                const float4 sv = s4[j];
                acc0[4 * j + 0] = fmaf(sv.x, w0, acc0[4 * j + 0]);
                acc0[4 * j + 1] = fmaf(sv.y, w0, acc0[4 * j + 1]);
                acc0[4 * j + 2] = fmaf(sv.z, w0, acc0[4 * j + 2]);
                acc0[4 * j + 3] = fmaf(sv.w, w0, acc0[4 * j + 3]);
                acc1[4 * j + 0] = fmaf(sv.x, w1, acc1[4 * j + 0]);
                acc1[4 * j + 1] = fmaf(sv.y, w1, acc1[4 * j + 1]);
                acc1[4 * j + 2] = fmaf(sv.z, w1, acc1[4 * j + 2]);
                acc1[4 * j + 3] = fmaf(sv.w, w1, acc1[4 * j + 3]);
            }
        }
    }

    // --- epilogue: BN + SiLU, store ---
    const int oA = o0, oB = o0 + 128;
    const float scA = g[oA] * rsqrtf(va[oA] + 1e-5f);
    const float shA = be[oA] - mu[oA] * scA;
    const float scB = g[oB] * rsqrtf(va[oB] + 1e-5f);
    const float shB = be[oB] - mu[oB] * scB;

#pragma unroll
    for (int i = 0; i < 16; ++i) {
        const int pi2 = p0 + half * 16 + i;
        const int b2 = pi2 / HW;
        const int hw2 = pi2 % HW;
        float* o_base = out + (size_t)b2 * 256 * HW + hw2;
        const float yA = acc0[i] * scA + shA;
        const float yB = acc1[i] * scB + shB;
        o_base[(size_t)oA * HW] = siluf_(yA);
        o_base[(size_t)oB * HW] = siluf_(yB);
    }
}

// ---------------------------------------------------------------------------
extern "C" void kernel_launch(void* const* d_in, const int* in_sizes, int n_in,
                              void* d_out, int out_size, void* d_ws, size_t ws_size,
                              hipStream_t stream)
{
    const float* x        = (const float*)d_in[0];
    const float* reduce_w = (const float*)d_in[1];
    const float* rg       = (const float*)d_in[2];
    const float* rb       = (const float*)d_in[3];
    const float* rm       = (const float*)d_in[4];
    const float* rv       = (const float*)d_in[5];
    const float* off_w    = (const float*)d_in[6];
    const float* off_b    = (const float*)d_in[7];
    const float* dcn_w    = (const float*)d_in[8];
    const float* dg       = (const float*)d_in[9];
    const float* db       = (const float*)d_in[10];
    const float* dm       = (const float*)d_in[11];
    const float* dv       = (const float*)d_in[12];

    float* ws  = (float*)d_ws;
    float* xm  = ws;                       // 8*128*6400  = 6,553,600
    float* om  = xm + 6553600;             // 8*27*6400   = 1,382,400
    float* WrT = om + 1382400;             // 512*128     = 65,536
    float* WoT = WrT + 65536;              // 1152*32     = 36,864
    float* Wd  = WoT + 36864;              // 9*128*256   = 294,912

    k0_prep<<<dim3(1530), dim3(256), 0, stream>>>(reduce_w, off_w, dcn_w, WrT, WoT, Wd);
    k1_reduce<<<dim3(800), dim3(256), 0, stream>>>(x, WrT, rg, rb, rm, rv, xm);
    k2_off<<<dim3(200, 3), dim3(256), 0, stream>>>(xm, WoT, off_b, om);
    k3_dcn<<<dim3(1600), dim3(256), 0, stream>>>(xm, om, Wd, dg, db, dm, dv, (float*)d_out);
}

// Round 5
// 486.501 us; speedup vs baseline: 1.6779x; 1.6779x over previous
//
#include <hip/hip_runtime.h>

constexpr int HW  = 6400;   // 80*80
constexpr int WW  = 80;

typedef __attribute__((ext_vector_type(8))) short short8;   // 8 bf16 = 4 VGPR
typedef __attribute__((ext_vector_type(4))) float f32x4;

__device__ __forceinline__ float sigmoidf_(float x) { return 1.f / (1.f + __expf(-x)); }
__device__ __forceinline__ float siluf_(float y) { return y / (1.f + __expf(-y)); }
__device__ __forceinline__ unsigned short f2bf(float f) {   // RNE f32->bf16
    unsigned u = __float_as_uint(f);
    u += 0x7FFFu + ((u >> 16) & 1u);
    return (unsigned short)(u >> 16);
}

// ---------------------------------------------------------------------------
// k0: weight prep
//   WrT[cs][m]   (512x128) fp32   from reduce_w
//   WoT[(c*9+q)*32+o] fp32        from off_w (o<27)
//   WdB bf16 in MFMA B-fragment layout:
//     chunk = ot*36 + ksg  (ot: o-tile 0..15, ksg: K-step 0..35)
//     WdB[chunk*512 + lane*8 + e] = bf16(dcn_w[o][c][tap])
//       o = ot*16 + (lane&15); kk = ksg*32 + (lane>>4)*8 + e; tap=kk>>7; c=kk&127
// ---------------------------------------------------------------------------
__global__ __launch_bounds__(256) void k0_prep(
    const float* __restrict__ rw, const float* __restrict__ ow,
    const float* __restrict__ dw,
    float* __restrict__ WrT, float* __restrict__ WoT, unsigned short* __restrict__ WdB)
{
    const int i = blockIdx.x * 256 + threadIdx.x;
    if (i < 65536) {                       // 512*128
        const int cs = i >> 7, m = i & 127;
        WrT[i] = rw[m * 512 + cs];
    }
    const int j = i - 65536;
    if (j >= 0 && j < 31104) {             // 1152*27
        const int r = j / 27, o = j % 27;
        WoT[r * 32 + o] = ow[o * 1152 + r];
    }
    const int l = j - 31104;
    if (l >= 0 && l < 294912) {            // 16*36*64*8
        const int e = l & 7;
        const int lane = (l >> 3) & 63;
        const int chunk = l >> 9;
        const int ot = chunk / 36, ksg = chunk % 36;
        const int kk = ksg * 32 + ((lane >> 4) << 3) + e;
        const int tap = kk >> 7, c = kk & 127;
        const int o = (ot << 4) + (lane & 15);
        WdB[l] = f2bf(dw[o * 1152 + c * 9 + tap]);
    }
}

// ---------------------------------------------------------------------------
// k1: space-to-depth + 1x1 conv (512->128) + BN + SiLU  ->  xm (8,128,80,80)
// ---------------------------------------------------------------------------
__global__ __launch_bounds__(256) void k1_reduce(
    const float* __restrict__ x, const float* __restrict__ WrT,
    const float* __restrict__ g, const float* __restrict__ be,
    const float* __restrict__ mu, const float* __restrict__ va,
    float* __restrict__ xm)
{
    const int t = threadIdx.x;
    const int lane = t & 63;
    const int m0 = __builtin_amdgcn_readfirstlane((t >> 6) * 32);
    const int pi = blockIdx.x * 64 + lane;
    const int b = pi / HW;
    const int hw = pi % HW;
    const int h = hw / WW, w = hw % WW;

    const float* xb = x + (size_t)b * 128 * 25600 + (2 * h) * 160 + 2 * w;

    float acc[32];
#pragma unroll
    for (int i = 0; i < 32; ++i) acc[i] = 0.f;

    for (int cs = 0; cs < 512; ++cs) {
        const int c = cs >> 2, sy = (cs >> 1) & 1, sx = cs & 1;
        const float xv = xb[c * 25600 + sy * 160 + sx];
        const float* wr = WrT + cs * 128 + m0;
#pragma unroll
        for (int i = 0; i < 32; ++i) acc[i] = fmaf(wr[i], xv, acc[i]);
    }

    float* op = xm + (size_t)b * 128 * HW + hw;
#pragma unroll
    for (int i = 0; i < 32; ++i) {
        const int m = m0 + i;
        const float sc = g[m] * rsqrtf(va[m] + 1e-5f);
        const float y = (acc[i] - mu[m]) * sc + be[m];
        op[(size_t)m * HW] = siluf_(y);
    }
}

// ---------------------------------------------------------------------------
// k2: 3x3 conv (128->27) + bias  ->  om (8,27,80,80)
// ---------------------------------------------------------------------------
__global__ __launch_bounds__(256) void k2_off(
    const float* __restrict__ xm, const float* __restrict__ WoT,
    const float* __restrict__ obias, float* __restrict__ om)
{
    const int pi = blockIdx.x * 256 + threadIdx.x;
    const int og = blockIdx.y;                      // 0..2
    const int b = pi / HW;
    const int hw = pi % HW;
    const int h = hw / WW, w = hw % WW;
    const float* xb = xm + (size_t)b * 128 * HW;

    float acc[9];
#pragma unroll
    for (int o = 0; o < 9; ++o) acc[o] = 0.f;

    for (int c = 0; c < 128; ++c) {
        float xq[9];
#pragma unroll
        for (int dy = 0; dy < 3; ++dy)
#pragma unroll
            for (int dx = 0; dx < 3; ++dx) {
                const int y = h + dy - 1, xx = w + dx - 1;
                const bool v = ((unsigned)y < 80u) && ((unsigned)xx < 80u);
                xq[dy * 3 + dx] = v ? xb[c * HW + y * WW + xx] : 0.f;
            }
#pragma unroll
        for (int q = 0; q < 9; ++q) {
            const float* wp = WoT + (c * 9 + q) * 32 + og * 9;
            const float xv = xq[q];
#pragma unroll
            for (int o = 0; o < 9; ++o) acc[o] = fmaf(xv, wp[o], acc[o]);
        }
    }

    float* op = om + (size_t)b * 27 * HW + hw;
#pragma unroll
    for (int o = 0; o < 9; ++o) op[(og * 9 + o) * HW] = acc[o] + obias[og * 9 + o];
}

// ---------------------------------------------------------------------------
// k3 v2: deform-sample -> bf16 LDS tile -> MFMA GEMM -> BN+SiLU
// block: 512 thr (8 waves), 64 px x 256 o. Wave grid 2(M) x 4(N):
//   wave tile 32 px x 64 o = 2 Mt x 4 Nt of 16x16, acc 2x4 f32x4.
// Per tap: S[64px][128c] bf16 in LDS (XOR-swizzled), double-buffered.
// Geometry (all 9 taps) precomputed once into LDS.
// ---------------------------------------------------------------------------
__global__ __launch_bounds__(512) void k3_dcn(
    const float* __restrict__ xm, const float* __restrict__ om,
    const unsigned short* __restrict__ WdB,
    const float* __restrict__ g, const float* __restrict__ be,
    const float* __restrict__ mu, const float* __restrict__ va,
    float* __restrict__ out)
{
    __shared__ __align__(16) unsigned short S[2][64 * 128];  // 2 x 16 KB
    __shared__ __align__(16) float4 geoW[9][64];             // 9 KB
    __shared__ __align__(16) int4   geoI[9][64];             // 9 KB

    const int t    = threadIdx.x;
    const int lane = t & 63;
    const int wave = t >> 6;
    const int p0   = blockIdx.x * 64;
    const int bb   = p0 / HW;
    const int hw0  = p0 % HW;

    // ---- geometry for all 9 taps (once) ----
    for (int it = t; it < 576; it += 512) {
        const int tap = it >> 6, px = it & 63;
        const int hw = hw0 + px;
        const int h = hw / WW, w = hw % WW;
        const float* ob = om + (size_t)bb * 27 * HW + hw;
        const float oy = ob[(2 * tap) * HW];
        const float ox = ob[(2 * tap + 1) * HW];
        const float mk = sigmoidf_(ob[(18 + tap) * HW]);
        float py  = (float)(h - 1 + tap / 3) + oy;
        float pxf = (float)(w - 1 + tap % 3) + ox;
        py  = fminf(fmaxf(py, -1000.f), 1000.f);
        pxf = fminf(fmaxf(pxf, -1000.f), 1000.f);
        const float fy = floorf(py), fx = floorf(pxf);
        const int y0 = (int)fy, x0 = (int)fx, y1 = y0 + 1, x1 = x0 + 1;
        const float wy = py - fy, wx = pxf - fx;
        const float vy0 = ((unsigned)y0 < 80u) ? 1.f : 0.f;
        const float vy1 = ((unsigned)y1 < 80u) ? 1.f : 0.f;
        const float vx0 = ((unsigned)x0 < 80u) ? 1.f : 0.f;
        const float vx1 = ((unsigned)x1 < 80u) ? 1.f : 0.f;
        float4 wv;
        wv.x = (1.f - wy) * (1.f - wx) * vy0 * vx0 * mk;
        wv.y = (1.f - wy) * wx * vy0 * vx1 * mk;
        wv.z = wy * (1.f - wx) * vy1 * vx0 * mk;
        wv.w = wy * wx * vy1 * vx1 * mk;
        const int cy0 = min(max(y0, 0), 79), cy1 = min(max(y1, 0), 79);
        const int cx0 = min(max(x0, 0), 79), cx1 = min(max(x1, 0), 79);
        int4 iv;
        iv.x = cy0 * WW + cx0; iv.y = cy0 * WW + cx1;
        iv.z = cy1 * WW + cx0; iv.w = cy1 * WW + cx1;
        geoW[tap][px] = wv;
        geoI[tap][px] = iv;
    }
    __syncthreads();

    const float* xb = xm + (size_t)bb * 128 * HW;

    // sampling role: px = lane, channels [wave*16, wave*16+16)
    auto SAMPLE = [&](int tap, int bufIdx) {
        const float4 wv = geoW[tap][lane];
        const int4  iv = geoI[tap][lane];
        const int px = lane, cg = wave;
#pragma unroll
        for (int half = 0; half < 2; ++half) {
            unsigned short hs[8];
#pragma unroll
            for (int j = 0; j < 8; ++j) {
                const int c = cg * 16 + half * 8 + j;
                const float* xc = xb + (size_t)c * HW;
                const float s = wv.x * xc[iv.x] + wv.y * xc[iv.y] +
                                wv.z * xc[iv.z] + wv.w * xc[iv.w];
                hs[j] = f2bf(s);
            }
            uint4 pk;
            pk.x = hs[0] | ((unsigned)hs[1] << 16);
            pk.y = hs[2] | ((unsigned)hs[3] << 16);
            pk.z = hs[4] | ((unsigned)hs[5] << 16);
            pk.w = hs[6] | ((unsigned)hs[7] << 16);
            const int cslot = cg * 2 + half;
            const int elem  = px * 128 + ((cslot ^ (px & 7)) << 3);
            *reinterpret_cast<uint4*>(&S[bufIdx][elem]) = pk;
        }
    };

    // gemm role
    const int wM = wave >> 2, wN = wave & 3;
    const int q = lane >> 4, ln = lane & 15;
    f32x4 acc[2][4] = {};

    auto GEMM = [&](int tap, int bufIdx) {
#pragma unroll
        for (int ks = 0; ks < 4; ++ks) {
            short8 a0, a1;
            {
                const int px = wM * 32 + 0 * 16 + ln;
                const int elem = px * 128 + (((ks * 4 + q) ^ (px & 7)) << 3);
                a0 = *reinterpret_cast<const short8*>(&S[bufIdx][elem]);
            }
            {
                const int px = wM * 32 + 1 * 16 + ln;
                const int elem = px * 128 + (((ks * 4 + q) ^ (px & 7)) << 3);
                a1 = *reinterpret_cast<const short8*>(&S[bufIdx][elem]);
            }
#pragma unroll
            for (int nt = 0; nt < 4; ++nt) {
                const int ot = wN * 4 + nt;
                const int chunk = ot * 36 + tap * 4 + ks;
                const short8 b = *reinterpret_cast<const short8*>(WdB + chunk * 512 + lane * 8);
                acc[0][nt] = __builtin_amdgcn_mfma_f32_16x16x32_bf16(a0, b, acc[0][nt], 0, 0, 0);
                acc[1][nt] = __builtin_amdgcn_mfma_f32_16x16x32_bf16(a1, b, acc[1][nt], 0, 0, 0);
            }
        }
    };

    SAMPLE(0, 0);
    __syncthreads();
    for (int tap = 0; tap < 9; ++tap) {
        if (tap < 8) SAMPLE(tap + 1, (tap + 1) & 1);
        GEMM(tap, tap & 1);
        __syncthreads();
    }

    // ---- epilogue: BN + SiLU, store ----
    float sc[4], sh[4];
#pragma unroll
    for (int nt = 0; nt < 4; ++nt) {
        const int o = wN * 64 + nt * 16 + ln;
        sc[nt] = g[o] * rsqrtf(va[o] + 1e-5f);
        sh[nt] = be[o] - mu[o] * sc[nt];
    }
#pragma unroll
    for (int mt = 0; mt < 2; ++mt)
#pragma unroll
        for (int nt = 0; nt < 4; ++nt) {
            const int o = wN * 64 + nt * 16 + ln;
            float* obase = out + (size_t)bb * 256 * HW + (size_t)o * HW;
#pragma unroll
            for (int r = 0; r < 4; ++r) {
                const int pxl = wM * 32 + mt * 16 + q * 4 + r;
                const float y = acc[mt][nt][r] * sc[nt] + sh[nt];
                obase[hw0 + pxl] = siluf_(y);
            }
        }
}

// ---------------------------------------------------------------------------
extern "C" void kernel_launch(void* const* d_in, const int* in_sizes, int n_in,
                              void* d_out, int out_size, void* d_ws, size_t ws_size,
                              hipStream_t stream)
{
    const float* x        = (const float*)d_in[0];
    const float* reduce_w = (const float*)d_in[1];
    const float* rg       = (const float*)d_in[2];
    const float* rb       = (const float*)d_in[3];
    const float* rm       = (const float*)d_in[4];
    const float* rv       = (const float*)d_in[5];
    const float* off_w    = (const float*)d_in[6];
    const float* off_b    = (const float*)d_in[7];
    const float* dcn_w    = (const float*)d_in[8];
    const float* dg       = (const float*)d_in[9];
    const float* db       = (const float*)d_in[10];
    const float* dm       = (const float*)d_in[11];
    const float* dv       = (const float*)d_in[12];

    float* ws  = (float*)d_ws;
    float* xm  = ws;                        // 8*128*6400  = 6,553,600 f
    float* om  = xm + 6553600;              // 8*27*6400   = 1,382,400 f
    float* WrT = om + 1382400;              // 65,536 f
    float* WoT = WrT + 65536;               // 36,864 f
    unsigned short* WdB = (unsigned short*)(WoT + 36864);  // 294,912 bf16

    k0_prep<<<dim3(1530), dim3(256), 0, stream>>>(reduce_w, off_w, dcn_w, WrT, WoT, WdB);
    k1_reduce<<<dim3(800), dim3(256), 0, stream>>>(x, WrT, rg, rb, rm, rv, xm);
    k2_off<<<dim3(200, 3), dim3(256), 0, stream>>>(xm, WoT, off_b, om);
    k3_dcn<<<dim3(800), dim3(512), 0, stream>>>(xm, om, WdB, dg, db, dm, dv, (float*)d_out);
}

// Round 6
// 308.097 us; speedup vs baseline: 2.6495x; 1.5791x over previous
//
#include <hip/hip_runtime.h>

constexpr int HW  = 6400;   // 80*80
constexpr int WW  = 80;

typedef __attribute__((ext_vector_type(8))) short short8;   // 8 bf16 = 4 VGPR
typedef __attribute__((ext_vector_type(4))) float f32x4;
typedef unsigned short ushort_t;

__device__ __forceinline__ float sigmoidf_(float x) { return 1.f / (1.f + __expf(-x)); }
__device__ __forceinline__ float siluf_(float y) { return y / (1.f + __expf(-y)); }
__device__ __forceinline__ ushort_t f2bf(float f) {   // RNE f32->bf16
    unsigned u = __float_as_uint(f);
    u += 0x7FFFu + ((u >> 16) & 1u);
    return (ushort_t)(u >> 16);
}
__device__ __forceinline__ float bf2f(ushort_t h) {
    return __uint_as_float(((unsigned)h) << 16);
}

// ---------------------------------------------------------------------------
// k0: weight prep
//   WrT[cs][m] (512x128) fp32
//   WoB bf16 MFMA-B frags: chunk = nf*36+ksg (nf 0..1), K = q*128+c, o = nf*16+(lane&15)
//   WdB bf16 MFMA-B frags: chunk = ot*36+ksg (ot 0..15), K = tap*128+c, o = ot*16+(lane&15)
// ---------------------------------------------------------------------------
__global__ __launch_bounds__(256) void k0_prep(
    const float* __restrict__ rw, const float* __restrict__ ow,
    const float* __restrict__ dw,
    float* __restrict__ WrT, ushort_t* __restrict__ WoB, ushort_t* __restrict__ WdB)
{
    const int i = blockIdx.x * 256 + threadIdx.x;
    if (i < 65536) {                       // 512*128
        const int cs = i >> 7, m = i & 127;
        WrT[i] = rw[m * 512 + cs];
    }
    const int j = i - 65536;
    if (j >= 0 && j < 36864) {             // 2*36*512
        const int e = j & 7;
        const int lane = (j >> 3) & 63;
        const int chunk = j >> 9;
        const int nf = chunk / 36, ksg = chunk % 36;
        const int kk = ksg * 32 + ((lane >> 4) << 3) + e;
        const int q = kk >> 7, c = kk & 127;
        const int o = (nf << 4) + (lane & 15);
        WoB[j] = (o < 27) ? f2bf(ow[o * 1152 + c * 9 + q]) : (ushort_t)0;
    }
    const int l = j - 36864;
    if (l >= 0 && l < 294912) {            // 16*36*512
        const int e = l & 7;
        const int lane = (l >> 3) & 63;
        const int chunk = l >> 9;
        const int ot = chunk / 36, ksg = chunk % 36;
        const int kk = ksg * 32 + ((lane >> 4) << 3) + e;
        const int tap = kk >> 7, c = kk & 127;
        const int o = (ot << 4) + (lane & 15);
        WdB[l] = f2bf(dw[o * 1152 + c * 9 + tap]);
    }
}

// ---------------------------------------------------------------------------
// k1: space-to-depth + 1x1 conv (512->128) + BN + SiLU -> xm_bf [b][hw][c] bf16
// ---------------------------------------------------------------------------
__global__ __launch_bounds__(256) void k1_reduce(
    const float* __restrict__ x, const float* __restrict__ WrT,
    const float* __restrict__ g, const float* __restrict__ be,
    const float* __restrict__ mu, const float* __restrict__ va,
    ushort_t* __restrict__ xm_bf)
{
    const int t = threadIdx.x;
    const int lane = t & 63;
    const int m0 = __builtin_amdgcn_readfirstlane((t >> 6) * 32);
    const int pi = blockIdx.x * 64 + lane;          // 0..51199
    const int b = pi / HW;
    const int hw = pi % HW;
    const int h = hw / WW, w = hw % WW;

    const float* xb = x + (size_t)b * 128 * 25600 + (2 * h) * 160 + 2 * w;

    float acc[32];
#pragma unroll
    for (int i = 0; i < 32; ++i) acc[i] = 0.f;

    for (int cs2 = 0; cs2 < 256; ++cs2) {           // (c, sy) pairs, float2 over sx
        const int c = cs2 >> 1, sy = cs2 & 1;
        const float2 xv = *reinterpret_cast<const float2*>(xb + c * 25600 + sy * 160);
        const float* wr0 = WrT + (cs2 * 2 + 0) * 128 + m0;
        const float* wr1 = WrT + (cs2 * 2 + 1) * 128 + m0;
#pragma unroll
        for (int i = 0; i < 32; ++i)
            acc[i] = fmaf(wr1[i], xv.y, fmaf(wr0[i], xv.x, acc[i]));
    }

    ushort_t hs[32];
#pragma unroll
    for (int i = 0; i < 32; ++i) {
        const int m = m0 + i;
        const float sc = g[m] * rsqrtf(va[m] + 1e-5f);
        const float y = (acc[i] - mu[m]) * sc + be[m];
        hs[i] = f2bf(siluf_(y));
    }
    ushort_t* op = xm_bf + (size_t)pi * 128 + m0;
#pragma unroll
    for (int v = 0; v < 4; ++v) {
        uint4 pk;
        pk.x = hs[v*8+0] | ((unsigned)hs[v*8+1] << 16);
        pk.y = hs[v*8+2] | ((unsigned)hs[v*8+3] << 16);
        pk.z = hs[v*8+4] | ((unsigned)hs[v*8+5] << 16);
        pk.w = hs[v*8+6] | ((unsigned)hs[v*8+7] << 16);
        *reinterpret_cast<uint4*>(op + v * 8) = pk;
    }
}

// ---------------------------------------------------------------------------
// k2: 3x3 conv (128->27) + bias via MFMA. M=64px/block, K=1152 (q*128+c), N=32.
// 256 thr = 4 waves; wave = M-tile of 16 px. A staged per-q from channel-last xm.
// ---------------------------------------------------------------------------
__global__ __launch_bounds__(256) void k2_off(
    const ushort_t* __restrict__ xm_bf, const ushort_t* __restrict__ WoB,
    const float* __restrict__ obias, float* __restrict__ om)
{
    __shared__ __align__(16) ushort_t A[2][64 * 128];   // 2 x 16 KB
    __shared__ __align__(16) float T[32 * 64];          // 8 KB

    const int t = threadIdx.x;
    const int lane = t & 63;
    const int wave = t >> 6;
    const int p0 = blockIdx.x * 64;
    const int bb = p0 / HW;
    const int hw0 = p0 % HW;

    // staging role: px = t&63, cg = wave (32 ch each)
    const int spx = t & 63;
    const int hws = hw0 + spx;
    const int hh = hws / WW, wwp = hws % WW;

    auto STAGE = [&](int q, int buf) {
        const int dy = q / 3 - 1, dx = q % 3 - 1;
        const int y = hh + dy, xx = wwp + dx;
        const bool valid = ((unsigned)y < 80u) && ((unsigned)xx < 80u);
        const ushort_t* src = xm_bf + ((size_t)bb * HW + y * WW + xx) * 128 + wave * 32;
#pragma unroll
        for (int s = 0; s < 4; ++s) {
            uint4 v = make_uint4(0u, 0u, 0u, 0u);
            if (valid) v = *reinterpret_cast<const uint4*>(src + s * 8);
            const int cslot = wave * 4 + s;
            *reinterpret_cast<uint4*>(&A[buf][spx * 128 + ((cslot ^ (spx & 7)) << 3)]) = v;
        }
    };

    const int q4 = lane >> 4, ln = lane & 15;
    f32x4 acc[2] = {};

    auto GEMM = [&](int q, int buf) {
#pragma unroll
        for (int ks = 0; ks < 4; ++ks) {
            const int px = wave * 16 + ln;
            const int elem = px * 128 + (((ks * 4 + q4) ^ (px & 7)) << 3);
            const short8 a = *reinterpret_cast<const short8*>(&A[buf][elem]);
#pragma unroll
            for (int nf = 0; nf < 2; ++nf) {
                const int chunk = nf * 36 + q * 4 + ks;
                const short8 b = *reinterpret_cast<const short8*>(WoB + chunk * 512 + lane * 8);
                acc[nf] = __builtin_amdgcn_mfma_f32_16x16x32_bf16(a, b, acc[nf], 0, 0, 0);
            }
        }
    };

    STAGE(0, 0);
    __syncthreads();
    for (int q = 0; q < 9; ++q) {
        if (q < 8) STAGE(q + 1, (q + 1) & 1);
        GEMM(q, q & 1);
        __syncthreads();
    }

    // scatter acc -> T[o][px], then coalesced store
#pragma unroll
    for (int nf = 0; nf < 2; ++nf)
#pragma unroll
        for (int r = 0; r < 4; ++r) {
            const int o = nf * 16 + ln;
            const int px = wave * 16 + q4 * 4 + r;
            T[o * 64 + px] = acc[nf][r];
        }
    __syncthreads();
    for (int i = t; i < 27 * 64; i += 256) {
        const int o = i >> 6, px = i & 63;
        om[((size_t)bb * 27 + o) * HW + hw0 + px] = T[i] + obias[o];
    }
}

// ---------------------------------------------------------------------------
// k3: deform-sample (channel-last bf16 gather) -> LDS -> MFMA -> BN+SiLU
// 512 thr (8 waves), 64 px x 256 o per block.
// ---------------------------------------------------------------------------
__global__ __launch_bounds__(512) void k3_dcn(
    const ushort_t* __restrict__ xm_bf, const float* __restrict__ om,
    const ushort_t* __restrict__ WdB,
    const float* __restrict__ g, const float* __restrict__ be,
    const float* __restrict__ mu, const float* __restrict__ va,
    float* __restrict__ out)
{
    __shared__ __align__(16) ushort_t S[2][64 * 128];  // 2 x 16 KB
    __shared__ __align__(16) float4 geoW[9][64];       // 9 KB
    __shared__ __align__(16) int4   geoI[9][64];       // 9 KB

    const int t    = threadIdx.x;
    const int lane = t & 63;
    const int wave = t >> 6;
    const int p0   = blockIdx.x * 64;
    const int bb   = p0 / HW;
    const int hw0  = p0 % HW;

    // ---- geometry for all 9 taps (once) ----
    for (int it = t; it < 576; it += 512) {
        const int tap = it >> 6, px = it & 63;
        const int hw = hw0 + px;
        const int h = hw / WW, w = hw % WW;
        const float* ob = om + (size_t)bb * 27 * HW + hw;
        const float oy = ob[(2 * tap) * HW];
        const float ox = ob[(2 * tap + 1) * HW];
        const float mk = sigmoidf_(ob[(18 + tap) * HW]);
        float py  = (float)(h - 1 + tap / 3) + oy;
        float pxf = (float)(w - 1 + tap % 3) + ox;
        py  = fminf(fmaxf(py, -1000.f), 1000.f);
        pxf = fminf(fmaxf(pxf, -1000.f), 1000.f);
        const float fy = floorf(py), fx = floorf(pxf);
        const int y0 = (int)fy, x0 = (int)fx, y1 = y0 + 1, x1 = x0 + 1;
        const float wy = py - fy, wx = pxf - fx;
        const float vy0 = ((unsigned)y0 < 80u) ? 1.f : 0.f;
        const float vy1 = ((unsigned)y1 < 80u) ? 1.f : 0.f;
        const float vx0 = ((unsigned)x0 < 80u) ? 1.f : 0.f;
        const float vx1 = ((unsigned)x1 < 80u) ? 1.f : 0.f;
        float4 wv;
        wv.x = (1.f - wy) * (1.f - wx) * vy0 * vx0 * mk;
        wv.y = (1.f - wy) * wx * vy0 * vx1 * mk;
        wv.z = wy * (1.f - wx) * vy1 * vx0 * mk;
        wv.w = wy * wx * vy1 * vx1 * mk;
        const int cy0 = min(max(y0, 0), 79), cy1 = min(max(y1, 0), 79);
        const int cx0 = min(max(x0, 0), 79), cx1 = min(max(x1, 0), 79);
        int4 iv;
        iv.x = cy0 * WW + cx0; iv.y = cy0 * WW + cx1;
        iv.z = cy1 * WW + cx0; iv.w = cy1 * WW + cx1;
        geoW[tap][px] = wv;
        geoI[tap][px] = iv;
    }
    __syncthreads();

    const ushort_t* xb = xm_bf + (size_t)bb * HW * 128;

    // sampling role: px = t>>3 (64), cg = t&7 (8 groups x 16 ch)
    const int spx = t >> 3;
    const int scg = t & 7;

    auto SAMPLE = [&](int tap, int bufIdx) {
        const float4 wv = geoW[tap][spx];
        const int4  iv = geoI[tap][spx];
        const uint4* c00 = reinterpret_cast<const uint4*>(xb + (size_t)iv.x * 128 + scg * 16);
        const uint4* c01 = reinterpret_cast<const uint4*>(xb + (size_t)iv.y * 128 + scg * 16);
        const uint4* c10 = reinterpret_cast<const uint4*>(xb + (size_t)iv.z * 128 + scg * 16);
        const uint4* c11 = reinterpret_cast<const uint4*>(xb + (size_t)iv.w * 128 + scg * 16);
#pragma unroll
        for (int half = 0; half < 2; ++half) {
            const uint4 a = c00[half], b = c01[half], c = c10[half], d = c11[half];
            const unsigned* ap = (const unsigned*)&a;
            const unsigned* bp = (const unsigned*)&b;
            const unsigned* cp = (const unsigned*)&c;
            const unsigned* dp = (const unsigned*)&d;
            unsigned pk[4];
#pragma unroll
            for (int u = 0; u < 4; ++u) {
                const float alo = __uint_as_float(ap[u] << 16), ahi = __uint_as_float(ap[u] & 0xFFFF0000u);
                const float blo = __uint_as_float(bp[u] << 16), bhi = __uint_as_float(bp[u] & 0xFFFF0000u);
                const float clo = __uint_as_float(cp[u] << 16), chi = __uint_as_float(cp[u] & 0xFFFF0000u);
                const float dlo = __uint_as_float(dp[u] << 16), dhi = __uint_as_float(dp[u] & 0xFFFF0000u);
                const float slo = wv.x * alo + wv.y * blo + wv.z * clo + wv.w * dlo;
                const float shi = wv.x * ahi + wv.y * bhi + wv.z * chi + wv.w * dhi;
                pk[u] = (unsigned)f2bf(slo) | ((unsigned)f2bf(shi) << 16);
            }
            const int cslot = scg * 2 + half;
            const int elem  = spx * 128 + ((cslot ^ (spx & 7)) << 3);
            *reinterpret_cast<uint4*>(&S[bufIdx][elem]) =
                make_uint4(pk[0], pk[1], pk[2], pk[3]);
        }
    };

    // gemm role
    const int wM = wave >> 2, wN = wave & 3;
    const int q = lane >> 4, ln = lane & 15;
    f32x4 acc[2][4] = {};

    auto GEMM = [&](int tap, int bufIdx) {
#pragma unroll
        for (int ks = 0; ks < 4; ++ks) {
            short8 a0, a1;
            {
                const int px = wM * 32 + ln;
                const int elem = px * 128 + (((ks * 4 + q) ^ (px & 7)) << 3);
                a0 = *reinterpret_cast<const short8*>(&S[bufIdx][elem]);
            }
            {
                const int px = wM * 32 + 16 + ln;
                const int elem = px * 128 + (((ks * 4 + q) ^ (px & 7)) << 3);
                a1 = *reinterpret_cast<const short8*>(&S[bufIdx][elem]);
            }
#pragma unroll
            for (int nt = 0; nt < 4; ++nt) {
                const int ot = wN * 4 + nt;
                const int chunk = ot * 36 + tap * 4 + ks;
                const short8 b = *reinterpret_cast<const short8*>(WdB + chunk * 512 + lane * 8);
                acc[0][nt] = __builtin_amdgcn_mfma_f32_16x16x32_bf16(a0, b, acc[0][nt], 0, 0, 0);
                acc[1][nt] = __builtin_amdgcn_mfma_f32_16x16x32_bf16(a1, b, acc[1][nt], 0, 0, 0);
            }
        }
    };

    SAMPLE(0, 0);
    __syncthreads();
    for (int tap = 0; tap < 9; ++tap) {
        if (tap < 8) SAMPLE(tap + 1, (tap + 1) & 1);
        GEMM(tap, tap & 1);
        __syncthreads();
    }

    // ---- epilogue: BN + SiLU, store ----
    float sc[4], sh[4];
#pragma unroll
    for (int nt = 0; nt < 4; ++nt) {
        const int o = wN * 64 + nt * 16 + ln;
        sc[nt] = g[o] * rsqrtf(va[o] + 1e-5f);
        sh[nt] = be[o] - mu[o] * sc[nt];
    }
#pragma unroll
    for (int mt = 0; mt < 2; ++mt)
#pragma unroll
        for (int nt = 0; nt < 4; ++nt) {
            const int o = wN * 64 + nt * 16 + ln;
            float* obase = out + (size_t)bb * 256 * HW + (size_t)o * HW;
#pragma unroll
            for (int r = 0; r < 4; ++r) {
                const int pxl = wM * 32 + mt * 16 + q * 4 + r;
                const float y = acc[mt][nt][r] * sc[nt] + sh[nt];
                obase[hw0 + pxl] = siluf_(y);
            }
        }
}

// ---------------------------------------------------------------------------
extern "C" void kernel_launch(void* const* d_in, const int* in_sizes, int n_in,
                              void* d_out, int out_size, void* d_ws, size_t ws_size,
                              hipStream_t stream)
{
    const float* x        = (const float*)d_in[0];
    const float* reduce_w = (const float*)d_in[1];
    const float* rg       = (const float*)d_in[2];
    const float* rb       = (const float*)d_in[3];
    const float* rm       = (const float*)d_in[4];
    const float* rv       = (const float*)d_in[5];
    const float* off_w    = (const float*)d_in[6];
    const float* off_b    = (const float*)d_in[7];
    const float* dcn_w    = (const float*)d_in[8];
    const float* dg       = (const float*)d_in[9];
    const float* db       = (const float*)d_in[10];
    const float* dm       = (const float*)d_in[11];
    const float* dv       = (const float*)d_in[12];

    float* ws  = (float*)d_ws;
    ushort_t* xm_bf = (ushort_t*)ws;                     // 6,553,600 bf16 = 3,276,800 f
    float* om  = ws + 3276800;                           // 1,382,400 f
    float* WrT = om + 1382400;                           // 65,536 f
    ushort_t* WoB = (ushort_t*)(WrT + 65536);            // 36,864 bf16 = 18,432 f
    ushort_t* WdB = (ushort_t*)(WrT + 65536 + 18432);    // 294,912 bf16

    k0_prep<<<dim3(1552), dim3(256), 0, stream>>>(reduce_w, off_w, dcn_w, WrT, WoB, WdB);
    k1_reduce<<<dim3(800), dim3(256), 0, stream>>>(x, WrT, rg, rb, rm, rv, xm_bf);
    k2_off<<<dim3(800), dim3(256), 0, stream>>>(xm_bf, WoB, off_b, om);
    k3_dcn<<<dim3(800), dim3(512), 0, stream>>>(xm_bf, om, WdB, dg, db, dm, dv, (float*)d_out);
}

// Round 7
// 275.023 us; speedup vs baseline: 2.9681x; 1.1203x over previous
//
#include <hip/hip_runtime.h>

constexpr int HW  = 6400;   // 80*80
constexpr int WW  = 80;

typedef __attribute__((ext_vector_type(8))) short short8;   // 8 bf16 = 4 VGPR
typedef __attribute__((ext_vector_type(4))) float f32x4;
typedef unsigned short ushort_t;

__device__ __forceinline__ float sigmoidf_(float x) { return 1.f / (1.f + __expf(-x)); }
__device__ __forceinline__ float siluf_(float y) { return y / (1.f + __expf(-y)); }
__device__ __forceinline__ ushort_t f2bf(float f) {   // RNE f32->bf16
    unsigned u = __float_as_uint(f);
    u += 0x7FFFu + ((u >> 16) & 1u);
    return (ushort_t)(u >> 16);
}
__device__ __forceinline__ float bf2f(ushort_t h) {
    return __uint_as_float(((unsigned)h) << 16);
}

// ---------------------------------------------------------------------------
// k0: weight prep (all MFMA B/A fragment layouts, bf16)
//  WBhi/WBlo: reduce_w split hi/lo. chunkW = nt*16+kks (nt 0..7, kks 0..15);
//             entry lane*8+e: o = nt*16+(lane&15), kk = kks*32+(lane>>4)*8+e (kk = cs)
//  WoB: off_w frags, chunk = nf*36+ksg (nf 0..1), K = q*128+c
//  WdB: dcn_w frags, chunk = ot*36+ksg (ot 0..15), K = tap*128+c
//  scr/shr: reduce-BN scale/shift fp32
// ---------------------------------------------------------------------------
__global__ __launch_bounds__(256) void k0_prep(
    const float* __restrict__ rw, const float* __restrict__ ow,
    const float* __restrict__ dw,
    const float* __restrict__ rg, const float* __restrict__ rb,
    const float* __restrict__ rm, const float* __restrict__ rv,
    ushort_t* __restrict__ WBhi, ushort_t* __restrict__ WBlo,
    ushort_t* __restrict__ WoB, ushort_t* __restrict__ WdB,
    float* __restrict__ scr, float* __restrict__ shr)
{
    const int i = blockIdx.x * 256 + threadIdx.x;
    if (blockIdx.x == 0 && threadIdx.x < 128) {
        const int m = threadIdx.x;
        const float sc = rg[m] * rsqrtf(rv[m] + 1e-5f);
        scr[m] = sc;
        shr[m] = rb[m] - rm[m] * sc;
    }
    if (i < 65536) {                       // WBhi/WBlo: 128 chunks * 512
        const int e = i & 7;
        const int lane = (i >> 3) & 63;
        const int chunkW = i >> 9;         // 0..127
        const int nt = chunkW >> 4, kks = chunkW & 15;
        const int kk = kks * 32 + ((lane >> 4) << 3) + e;   // cs 0..511
        const int o = (nt << 4) + (lane & 15);              // out ch 0..127
        const float w = rw[o * 512 + kk];
        const ushort_t hi = f2bf(w);
        WBhi[i] = hi;
        WBlo[i] = f2bf(w - bf2f(hi));
    }
    const int j = i - 65536;
    if (j >= 0 && j < 36864) {             // WoB: 2*36*512
        const int e = j & 7;
        const int lane = (j >> 3) & 63;
        const int chunk = j >> 9;
        const int nf = chunk / 36, ksg = chunk % 36;
        const int kk = ksg * 32 + ((lane >> 4) << 3) + e;
        const int q = kk >> 7, c = kk & 127;
        const int o = (nf << 4) + (lane & 15);
        WoB[j] = (o < 27) ? f2bf(ow[o * 1152 + c * 9 + q]) : (ushort_t)0;
    }
    const int l = j - 36864;
    if (l >= 0 && l < 294912) {            // WdB: 16*36*512
        const int e = l & 7;
        const int lane = (l >> 3) & 63;
        const int chunk = l >> 9;
        const int ot = chunk / 36, ksg = chunk % 36;
        const int kk = ksg * 32 + ((lane >> 4) << 3) + e;
        const int tap = kk >> 7, c = kk & 127;
        const int o = (ot << 4) + (lane & 15);
        WdB[l] = f2bf(dw[o * 1152 + c * 9 + tap]);
    }
}

// ---------------------------------------------------------------------------
// k1 v2: space-to-depth + 1x1 conv as split-precision bf16 MFMA GEMM.
// D[o][px] = W(128 x 512) . P(512 x 64px): A-operand = W (hi+lo), B = P (hi+lo).
// 3 terms: Whi*Phi + Whi*Plo + Wlo*Phi (fp32 accum) ~= fp32 GEMM.
// 256 thr = 4 waves; wave = px-tile (16 px), all 8 o-tiles; K staged in 4
// chunks of 128 (XOR-swizzled LDS, double-buffered).
// Epilogue: BN+SiLU, packed bf16 stores to channel-last xm_bf[pi][c].
// ---------------------------------------------------------------------------
__global__ __launch_bounds__(256) void k1_reduce(
    const float* __restrict__ x,
    const ushort_t* __restrict__ WBhi, const ushort_t* __restrict__ WBlo,
    const float* __restrict__ scr, const float* __restrict__ shr,
    ushort_t* __restrict__ xm_bf)
{
    __shared__ __align__(16) ushort_t Ahi[2][64 * 128];  // 2 x 16 KB
    __shared__ __align__(16) ushort_t Alo[2][64 * 128];  // 2 x 16 KB

    const int t    = threadIdx.x;
    const int lane = t & 63;
    const int wave = t >> 6;
    const int p0   = blockIdx.x * 64;
    const int bb   = p0 / HW;
    const int hw0  = p0 % HW;

    // staging role: px = t>>2 (16 px per wave, consecutive lanes vary cg)
    const int spx = t >> 2, scg = t & 3;
    const int hws = hw0 + spx;
    const int hh = hws / WW, wwp = hws % WW;
    const float* xb = x + (size_t)bb * 128 * 25600 + (2 * hh) * 160 + 2 * wwp;

    auto STAGE = [&](int kc, int buf) {
        const int c0 = kc * 32;
#pragma unroll
        for (int cc = 0; cc < 8; ++cc) {
            const int cidx = scg * 8 + cc;          // 0..31
            const int c = c0 + cidx;
            const float2 r0 = *reinterpret_cast<const float2*>(xb + c * 25600);
            const float2 r1 = *reinterpret_cast<const float2*>(xb + c * 25600 + 160);
            const ushort_t h0 = f2bf(r0.x), h1 = f2bf(r0.y);
            const ushort_t h2 = f2bf(r1.x), h3 = f2bf(r1.y);
            const ushort_t l0 = f2bf(r0.x - bf2f(h0)), l1 = f2bf(r0.y - bf2f(h1));
            const ushort_t l2 = f2bf(r1.x - bf2f(h2)), l3 = f2bf(r1.y - bf2f(h3));
            // kk' = cidx*4 + {0:(sy0,sx0),1:(sy0,sx1),2:(sy1,sx0),3:(sy1,sx1)}
            const int slot = cidx >> 1, off = (cidx & 1) * 4;
            const int elem = spx * 128 + ((slot ^ (spx & 7)) << 3) + off;
            *reinterpret_cast<uint2*>(&Ahi[buf][elem]) =
                make_uint2(h0 | ((unsigned)h1 << 16), h2 | ((unsigned)h3 << 16));
            *reinterpret_cast<uint2*>(&Alo[buf][elem]) =
                make_uint2(l0 | ((unsigned)l1 << 16), l2 | ((unsigned)l3 << 16));
        }
    };

    const int q = lane >> 4, ln = lane & 15;
    f32x4 acc[8] = {};

    auto GEMM = [&](int kc, int buf) {
#pragma unroll
        for (int ks = 0; ks < 4; ++ks) {
            const int px = wave * 16 + ln;
            const int elem = px * 128 + (((ks * 4 + q) ^ (px & 7)) << 3);
            const short8 phi = *reinterpret_cast<const short8*>(&Ahi[buf][elem]);
            const short8 plo = *reinterpret_cast<const short8*>(&Alo[buf][elem]);
            const int kks = kc * 4 + ks;
#pragma unroll
            for (int nt = 0; nt < 8; ++nt) {
                const int chunkW = (nt << 4) + kks;
                const short8 whi = *reinterpret_cast<const short8*>(WBhi + chunkW * 512 + lane * 8);
                const short8 wlo = *reinterpret_cast<const short8*>(WBlo + chunkW * 512 + lane * 8);
                acc[nt] = __builtin_amdgcn_mfma_f32_16x16x32_bf16(whi, phi, acc[nt], 0, 0, 0);
                acc[nt] = __builtin_amdgcn_mfma_f32_16x16x32_bf16(whi, plo, acc[nt], 0, 0, 0);
                acc[nt] = __builtin_amdgcn_mfma_f32_16x16x32_bf16(wlo, phi, acc[nt], 0, 0, 0);
            }
        }
    };

    STAGE(0, 0);
    __syncthreads();
    for (int kc = 0; kc < 4; ++kc) {
        if (kc < 3) STAGE(kc + 1, (kc + 1) & 1);
        GEMM(kc, kc & 1);
        __syncthreads();
    }

    // epilogue: D[o][px] -> lane has px = wave*16+ln, o = nt*16 + q*4 + r
    const int pi = p0 + wave * 16 + ln;
    ushort_t* op = xm_bf + (size_t)pi * 128;
#pragma unroll
    for (int nt = 0; nt < 8; ++nt) {
        const int ob = nt * 16 + q * 4;
        const float4 s4 = *reinterpret_cast<const float4*>(scr + ob);
        const float4 b4 = *reinterpret_cast<const float4*>(shr + ob);
        const float y0 = siluf_(acc[nt][0] * s4.x + b4.x);
        const float y1 = siluf_(acc[nt][1] * s4.y + b4.y);
        const float y2 = siluf_(acc[nt][2] * s4.z + b4.z);
        const float y3 = siluf_(acc[nt][3] * s4.w + b4.w);
        *reinterpret_cast<uint2*>(op + ob) =
            make_uint2(f2bf(y0) | ((unsigned)f2bf(y1) << 16),
                       f2bf(y2) | ((unsigned)f2bf(y3) << 16));
    }
}

// ---------------------------------------------------------------------------
// k2: 3x3 conv (128->27) + bias via MFMA. M=64px/block, K=1152, N=32.
// ---------------------------------------------------------------------------
__global__ __launch_bounds__(256) void k2_off(
    const ushort_t* __restrict__ xm_bf, const ushort_t* __restrict__ WoB,
    const float* __restrict__ obias, float* __restrict__ om)
{
    __shared__ __align__(16) ushort_t A[2][64 * 128];   // 2 x 16 KB
    __shared__ __align__(16) float T[32 * 64];          // 8 KB

    const int t = threadIdx.x;
    const int lane = t & 63;
    const int wave = t >> 6;
    const int p0 = blockIdx.x * 64;
    const int bb = p0 / HW;
    const int hw0 = p0 % HW;

    const int spx = t & 63;
    const int hws = hw0 + spx;
    const int hh = hws / WW, wwp = hws % WW;

    auto STAGE = [&](int q, int buf) {
        const int dy = q / 3 - 1, dx = q % 3 - 1;
        const int y = hh + dy, xx = wwp + dx;
        const bool valid = ((unsigned)y < 80u) && ((unsigned)xx < 80u);
        const ushort_t* src = xm_bf + ((size_t)bb * HW + y * WW + xx) * 128 + wave * 32;
#pragma unroll
        for (int s = 0; s < 4; ++s) {
            uint4 v = make_uint4(0u, 0u, 0u, 0u);
            if (valid) v = *reinterpret_cast<const uint4*>(src + s * 8);
            const int cslot = wave * 4 + s;
            *reinterpret_cast<uint4*>(&A[buf][spx * 128 + ((cslot ^ (spx & 7)) << 3)]) = v;
        }
    };

    const int q4 = lane >> 4, ln = lane & 15;
    f32x4 acc[2] = {};

    auto GEMM = [&](int q, int buf) {
#pragma unroll
        for (int ks = 0; ks < 4; ++ks) {
            const int px = wave * 16 + ln;
            const int elem = px * 128 + (((ks * 4 + q4) ^ (px & 7)) << 3);
            const short8 a = *reinterpret_cast<const short8*>(&A[buf][elem]);
#pragma unroll
            for (int nf = 0; nf < 2; ++nf) {
                const int chunk = nf * 36 + q * 4 + ks;
                const short8 b = *reinterpret_cast<const short8*>(WoB + chunk * 512 + lane * 8);
                acc[nf] = __builtin_amdgcn_mfma_f32_16x16x32_bf16(a, b, acc[nf], 0, 0, 0);
            }
        }
    };

    STAGE(0, 0);
    __syncthreads();
    for (int q = 0; q < 9; ++q) {
        if (q < 8) STAGE(q + 1, (q + 1) & 1);
        GEMM(q, q & 1);
        __syncthreads();
    }

#pragma unroll
    for (int nf = 0; nf < 2; ++nf)
#pragma unroll
        for (int r = 0; r < 4; ++r) {
            const int o = nf * 16 + ln;
            const int px = wave * 16 + q4 * 4 + r;
            T[o * 64 + px] = acc[nf][r];
        }
    __syncthreads();
    for (int i = t; i < 27 * 64; i += 256) {
        const int o = i >> 6, px = i & 63;
        om[((size_t)bb * 27 + o) * HW + hw0 + px] = T[i] + obias[o];
    }
}

// ---------------------------------------------------------------------------
// k3: deform-sample (channel-last bf16 gather) -> LDS -> MFMA -> BN+SiLU
// 512 thr (8 waves), 64 px x 256 o per block.
// ---------------------------------------------------------------------------
__global__ __launch_bounds__(512) void k3_dcn(
    const ushort_t* __restrict__ xm_bf, const float* __restrict__ om,
    const ushort_t* __restrict__ WdB,
    const float* __restrict__ g, const float* __restrict__ be,
    const float* __restrict__ mu, const float* __restrict__ va,
    float* __restrict__ out)
{
    __shared__ __align__(16) ushort_t S[2][64 * 128];  // 2 x 16 KB
    __shared__ __align__(16) float4 geoW[9][64];       // 9 KB
    __shared__ __align__(16) int4   geoI[9][64];       // 9 KB

    const int t    = threadIdx.x;
    const int lane = t & 63;
    const int wave = t >> 6;
    const int p0   = blockIdx.x * 64;
    const int bb   = p0 / HW;
    const int hw0  = p0 % HW;

    for (int it = t; it < 576; it += 512) {
        const int tap = it >> 6, px = it & 63;
        const int hw = hw0 + px;
        const int h = hw / WW, w = hw % WW;
        const float* ob = om + (size_t)bb * 27 * HW + hw;
        const float oy = ob[(2 * tap) * HW];
        const float ox = ob[(2 * tap + 1) * HW];
        const float mk = sigmoidf_(ob[(18 + tap) * HW]);
        float py  = (float)(h - 1 + tap / 3) + oy;
        float pxf = (float)(w - 1 + tap % 3) + ox;
        py  = fminf(fmaxf(py, -1000.f), 1000.f);
        pxf = fminf(fmaxf(pxf, -1000.f), 1000.f);
        const float fy = floorf(py), fx = floorf(pxf);
        const int y0 = (int)fy, x0 = (int)fx, y1 = y0 + 1, x1 = x0 + 1;
        const float wy = py - fy, wx = pxf - fx;
        const float vy0 = ((unsigned)y0 < 80u) ? 1.f : 0.f;
        const float vy1 = ((unsigned)y1 < 80u) ? 1.f : 0.f;
        const float vx0 = ((unsigned)x0 < 80u) ? 1.f : 0.f;
        const float vx1 = ((unsigned)x1 < 80u) ? 1.f : 0.f;
        float4 wv;
        wv.x = (1.f - wy) * (1.f - wx) * vy0 * vx0 * mk;
        wv.y = (1.f - wy) * wx * vy0 * vx1 * mk;
        wv.z = wy * (1.f - wx) * vy1 * vx0 * mk;
        wv.w = wy * wx * vy1 * vx1 * mk;
        const int cy0 = min(max(y0, 0), 79), cy1 = min(max(y1, 0), 79);
        const int cx0 = min(max(x0, 0), 79), cx1 = min(max(x1, 0), 79);
        int4 iv;
        iv.x = cy0 * WW + cx0; iv.y = cy0 * WW + cx1;
        iv.z = cy1 * WW + cx0; iv.w = cy1 * WW + cx1;
        geoW[tap][px] = wv;
        geoI[tap][px] = iv;
    }
    __syncthreads();

    const ushort_t* xb = xm_bf + (size_t)bb * HW * 128;

    const int spx = t >> 3;
    const int scg = t & 7;

    auto SAMPLE = [&](int tap, int bufIdx) {
        const float4 wv = geoW[tap][spx];
        const int4  iv = geoI[tap][spx];
        const uint4* c00 = reinterpret_cast<const uint4*>(xb + (size_t)iv.x * 128 + scg * 16);
        const uint4* c01 = reinterpret_cast<const uint4*>(xb + (size_t)iv.y * 128 + scg * 16);
        const uint4* c10 = reinterpret_cast<const uint4*>(xb + (size_t)iv.z * 128 + scg * 16);
        const uint4* c11 = reinterpret_cast<const uint4*>(xb + (size_t)iv.w * 128 + scg * 16);
#pragma unroll
        for (int half = 0; half < 2; ++half) {
            const uint4 a = c00[half], b = c01[half], c = c10[half], d = c11[half];
            const unsigned* ap = (const unsigned*)&a;
            const unsigned* bp = (const unsigned*)&b;
            const unsigned* cp = (const unsigned*)&c;
            const unsigned* dp = (const unsigned*)&d;
            unsigned pk[4];
#pragma unroll
            for (int u = 0; u < 4; ++u) {
                const float alo = __uint_as_float(ap[u] << 16), ahi = __uint_as_float(ap[u] & 0xFFFF0000u);
                const float blo = __uint_as_float(bp[u] << 16), bhi = __uint_as_float(bp[u] & 0xFFFF0000u);
                const float clo = __uint_as_float(cp[u] << 16), chi = __uint_as_float(cp[u] & 0xFFFF0000u);
                const float dlo = __uint_as_float(dp[u] << 16), dhi = __uint_as_float(dp[u] & 0xFFFF0000u);
                const float slo = wv.x * alo + wv.y * blo + wv.z * clo + wv.w * dlo;
                const float shi = wv.x * ahi + wv.y * bhi + wv.z * chi + wv.w * dhi;
                pk[u] = (unsigned)f2bf(slo) | ((unsigned)f2bf(shi) << 16);
            }
            const int cslot = scg * 2 + half;
            const int elem  = spx * 128 + ((cslot ^ (spx & 7)) << 3);
            *reinterpret_cast<uint4*>(&S[bufIdx][elem]) =
                make_uint4(pk[0], pk[1], pk[2], pk[3]);
        }
    };

    const int wM = wave >> 2, wN = wave & 3;
    const int q = lane >> 4, ln = lane & 15;
    f32x4 acc[2][4] = {};

    auto GEMM = [&](int tap, int bufIdx) {
#pragma unroll
        for (int ks = 0; ks < 4; ++ks) {
            short8 a0, a1;
            {
                const int px = wM * 32 + ln;
                const int elem = px * 128 + (((ks * 4 + q) ^ (px & 7)) << 3);
                a0 = *reinterpret_cast<const short8*>(&S[bufIdx][elem]);
            }
            {
                const int px = wM * 32 + 16 + ln;
                const int elem = px * 128 + (((ks * 4 + q) ^ (px & 7)) << 3);
                a1 = *reinterpret_cast<const short8*>(&S[bufIdx][elem]);
            }
#pragma unroll
            for (int nt = 0; nt < 4; ++nt) {
                const int ot = wN * 4 + nt;
                const int chunk = ot * 36 + tap * 4 + ks;
                const short8 b = *reinterpret_cast<const short8*>(WdB + chunk * 512 + lane * 8);
                acc[0][nt] = __builtin_amdgcn_mfma_f32_16x16x32_bf16(a0, b, acc[0][nt], 0, 0, 0);
                acc[1][nt] = __builtin_amdgcn_mfma_f32_16x16x32_bf16(a1, b, acc[1][nt], 0, 0, 0);
            }
        }
    };

    SAMPLE(0, 0);
    __syncthreads();
    for (int tap = 0; tap < 9; ++tap) {
        if (tap < 8) SAMPLE(tap + 1, (tap + 1) & 1);
        GEMM(tap, tap & 1);
        __syncthreads();
    }

    float sc[4], sh[4];
#pragma unroll
    for (int nt = 0; nt < 4; ++nt) {
        const int o = wN * 64 + nt * 16 + ln;
        sc[nt] = g[o] * rsqrtf(va[o] + 1e-5f);
        sh[nt] = be[o] - mu[o] * sc[nt];
    }
#pragma unroll
    for (int mt = 0; mt < 2; ++mt)
#pragma unroll
        for (int nt = 0; nt < 4; ++nt) {
            const int o = wN * 64 + nt * 16 + ln;
            float* obase = out + (size_t)bb * 256 * HW + (size_t)o * HW;
            float4 st;
            st.x = siluf_(acc[mt][nt][0] * sc[nt] + sh[nt]);
            st.y = siluf_(acc[mt][nt][1] * sc[nt] + sh[nt]);
            st.z = siluf_(acc[mt][nt][2] * sc[nt] + sh[nt]);
            st.w = siluf_(acc[mt][nt][3] * sc[nt] + sh[nt]);
            *reinterpret_cast<float4*>(obase + hw0 + wM * 32 + mt * 16 + q * 4) = st;
        }
}

// ---------------------------------------------------------------------------
extern "C" void kernel_launch(void* const* d_in, const int* in_sizes, int n_in,
                              void* d_out, int out_size, void* d_ws, size_t ws_size,
                              hipStream_t stream)
{
    const float* x        = (const float*)d_in[0];
    const float* reduce_w = (const float*)d_in[1];
    const float* rg       = (const float*)d_in[2];
    const float* rb       = (const float*)d_in[3];
    const float* rm       = (const float*)d_in[4];
    const float* rv       = (const float*)d_in[5];
    const float* off_w    = (const float*)d_in[6];
    const float* off_b    = (const float*)d_in[7];
    const float* dcn_w    = (const float*)d_in[8];
    const float* dg       = (const float*)d_in[9];
    const float* db       = (const float*)d_in[10];
    const float* dm       = (const float*)d_in[11];
    const float* dv       = (const float*)d_in[12];

    float* ws  = (float*)d_ws;
    ushort_t* xm_bf = (ushort_t*)ws;                 // 6,553,600 bf16
    float* om   = ws + 3276800;                      // 1,382,400 f
    ushort_t* WBhi = (ushort_t*)(om + 1382400);      // 65,536 bf16
    ushort_t* WBlo = WBhi + 65536;                   // 65,536 bf16
    ushort_t* WoB  = WBlo + 65536;                   // 36,864 bf16
    ushort_t* WdB  = WoB + 36864;                    // 294,912 bf16
    float* scr = (float*)(WdB + 294912);             // 128 f
    float* shr = scr + 128;                          // 128 f

    k0_prep<<<dim3(1552), dim3(256), 0, stream>>>(reduce_w, off_w, dcn_w,
                                                  rg, rb, rm, rv,
                                                  WBhi, WBlo, WoB, WdB, scr, shr);
    k1_reduce<<<dim3(800), dim3(256), 0, stream>>>(x, WBhi, WBlo, scr, shr, xm_bf);
    k2_off<<<dim3(800), dim3(256), 0, stream>>>(xm_bf, WoB, off_b, om);
    k3_dcn<<<dim3(800), dim3(512), 0, stream>>>(xm_bf, om, WdB, dg, db, dm, dv, (float*)d_out);
}

// Round 8
// 194.904 us; speedup vs baseline: 4.1882x; 1.4111x over previous
//
#include <hip/hip_runtime.h>

constexpr int HW  = 6400;   // 80*80
constexpr int WW  = 80;

typedef __attribute__((ext_vector_type(8))) short short8;   // 8 bf16 = 4 VGPR
typedef __attribute__((ext_vector_type(4))) float f32x4;
typedef unsigned short ushort_t;

__device__ __forceinline__ float sigmoidf_(float x) { return 1.f / (1.f + __expf(-x)); }
__device__ __forceinline__ float siluf_(float y) { return y / (1.f + __expf(-y)); }
__device__ __forceinline__ ushort_t f2bf(float f) {   // RNE f32->bf16
    unsigned u = __float_as_uint(f);
    u += 0x7FFFu + ((u >> 16) & 1u);
    return (ushort_t)(u >> 16);
}
__device__ __forceinline__ float bf2f(ushort_t h) {
    return __uint_as_float(((unsigned)h) << 16);
}

// ---------------------------------------------------------------------------
// k0: weight prep (bf16 MFMA fragment layouts)
//  WB:  reduce_w frags. chunk = nt*16+kks (nt 0..7, kks 0..15);
//       entry lane*8+e: o = nt*16+(lane&15), kk = kks*32+(lane>>4)*8+e (kk = cs)
//  WoB: off_w frags, chunk = nf*36+ksg (nf 0..1), K = q*128+c
//  WdB: dcn_w frags, chunk = ot*36+ksg (ot 0..15), K = tap*128+c
//  scr/shr: reduce-BN scale/shift fp32
// ---------------------------------------------------------------------------
__global__ __launch_bounds__(256) void k0_prep(
    const float* __restrict__ rw, const float* __restrict__ ow,
    const float* __restrict__ dw,
    const float* __restrict__ rg, const float* __restrict__ rb,
    const float* __restrict__ rm, const float* __restrict__ rv,
    ushort_t* __restrict__ WB,
    ushort_t* __restrict__ WoB, ushort_t* __restrict__ WdB,
    float* __restrict__ scr, float* __restrict__ shr)
{
    const int i = blockIdx.x * 256 + threadIdx.x;
    if (blockIdx.x == 0 && threadIdx.x < 128) {
        const int m = threadIdx.x;
        const float sc = rg[m] * rsqrtf(rv[m] + 1e-5f);
        scr[m] = sc;
        shr[m] = rb[m] - rm[m] * sc;
    }
    if (i < 65536) {                       // WB: 128 chunks * 512
        const int e = i & 7;
        const int lane = (i >> 3) & 63;
        const int chunkW = i >> 9;         // 0..127
        const int nt = chunkW >> 4, kks = chunkW & 15;
        const int kk = kks * 32 + ((lane >> 4) << 3) + e;   // cs 0..511
        const int o = (nt << 4) + (lane & 15);              // out ch 0..127
        WB[i] = f2bf(rw[o * 512 + kk]);
    }
    const int j = i - 65536;
    if (j >= 0 && j < 36864) {             // WoB: 2*36*512
        const int e = j & 7;
        const int lane = (j >> 3) & 63;
        const int chunk = j >> 9;
        const int nf = chunk / 36, ksg = chunk % 36;
        const int kk = ksg * 32 + ((lane >> 4) << 3) + e;
        const int q = kk >> 7, c = kk & 127;
        const int o = (nf << 4) + (lane & 15);
        WoB[j] = (o < 27) ? f2bf(ow[o * 1152 + c * 9 + q]) : (ushort_t)0;
    }
    const int l = j - 36864;
    if (l >= 0 && l < 294912) {            // WdB: 16*36*512
        const int e = l & 7;
        const int lane = (l >> 3) & 63;
        const int chunk = l >> 9;
        const int ot = chunk / 36, ksg = chunk % 36;
        const int kk = ksg * 32 + ((lane >> 4) << 3) + e;
        const int tap = kk >> 7, c = kk & 127;
        const int o = (ot << 4) + (lane & 15);
        WdB[l] = f2bf(dw[o * 1152 + c * 9 + tap]);
    }
}

// ---------------------------------------------------------------------------
// k1 v3: space-to-depth + 1x1 conv as bf16 MFMA, NO LDS.
// D[o][px] = W(128x512) . P(512x64px). 256 thr = 4 waves; wave owns 16 px,
// all 8 o-tiles. Each lane builds its own P-fragment from global:
//   px = wave*16+ln; per kks: 8 kk = 2 channels x 4 subpix = 4 float2 loads.
// Lanes 0..15 -> consecutive px -> coalesced stride-8B segments.
// Epilogue: BN+SiLU, packed bf16 stores to channel-last xm_bf[pi][c].
// ---------------------------------------------------------------------------
__global__ __launch_bounds__(256) void k1_reduce(
    const float* __restrict__ x,
    const ushort_t* __restrict__ WB,
    const float* __restrict__ scr, const float* __restrict__ shr,
    ushort_t* __restrict__ xm_bf)
{
    const int t    = threadIdx.x;
    const int lane = t & 63;
    const int wave = t >> 6;
    const int q = lane >> 4, ln = lane & 15;
    const int p0 = blockIdx.x * 64;
    const int bb = p0 / HW;
    const int px = wave * 16 + ln;
    const int hw = (p0 % HW) + px;
    const int h = hw / WW, w = hw % WW;
    const float* xb = x + (size_t)bb * 128 * 25600 + (2 * h) * 160 + 2 * w;

    f32x4 acc[8] = {};

#pragma unroll 4
    for (int kks = 0; kks < 16; ++kks) {
        const int c0 = kks * 8 + q * 2;       // 2 channels per fragment
        const float* pc0 = xb + (size_t)c0 * 25600;
        const float* pc1 = pc0 + 25600;
        const float2 a0 = *reinterpret_cast<const float2*>(pc0);
        const float2 a1 = *reinterpret_cast<const float2*>(pc0 + 160);
        const float2 b0 = *reinterpret_cast<const float2*>(pc1);
        const float2 b1 = *reinterpret_cast<const float2*>(pc1 + 160);
        short8 p;
        p[0] = (short)f2bf(a0.x); p[1] = (short)f2bf(a0.y);
        p[2] = (short)f2bf(a1.x); p[3] = (short)f2bf(a1.y);
        p[4] = (short)f2bf(b0.x); p[5] = (short)f2bf(b0.y);
        p[6] = (short)f2bf(b1.x); p[7] = (short)f2bf(b1.y);
#pragma unroll
        for (int nt = 0; nt < 8; ++nt) {
            const short8 wf = *reinterpret_cast<const short8*>(WB + ((nt << 4) + kks) * 512 + lane * 8);
            acc[nt] = __builtin_amdgcn_mfma_f32_16x16x32_bf16(wf, p, acc[nt], 0, 0, 0);
        }
    }

    // epilogue: D[o][px] -> lane has px (col), o = nt*16 + q*4 + r (row)
    const int pi = p0 + px;
    ushort_t* op = xm_bf + (size_t)pi * 128;
#pragma unroll
    for (int nt = 0; nt < 8; ++nt) {
        const int ob = nt * 16 + q * 4;
        const float4 s4 = *reinterpret_cast<const float4*>(scr + ob);
        const float4 b4 = *reinterpret_cast<const float4*>(shr + ob);
        const float y0 = siluf_(acc[nt][0] * s4.x + b4.x);
        const float y1 = siluf_(acc[nt][1] * s4.y + b4.y);
        const float y2 = siluf_(acc[nt][2] * s4.z + b4.z);
        const float y3 = siluf_(acc[nt][3] * s4.w + b4.w);
        *reinterpret_cast<uint2*>(op + ob) =
            make_uint2(f2bf(y0) | ((unsigned)f2bf(y1) << 16),
                       f2bf(y2) | ((unsigned)f2bf(y3) << 16));
    }
}

// ---------------------------------------------------------------------------
// k2: 3x3 conv (128->27) + bias via MFMA. M=64px/block, K=1152, N=32.
// ---------------------------------------------------------------------------
__global__ __launch_bounds__(256) void k2_off(
    const ushort_t* __restrict__ xm_bf, const ushort_t* __restrict__ WoB,
    const float* __restrict__ obias, float* __restrict__ om)
{
    __shared__ __align__(16) ushort_t A[2][64 * 128];   // 2 x 16 KB
    __shared__ __align__(16) float T[32 * 64];          // 8 KB

    const int t = threadIdx.x;
    const int lane = t & 63;
    const int wave = t >> 6;
    const int p0 = blockIdx.x * 64;
    const int bb = p0 / HW;
    const int hw0 = p0 % HW;

    const int spx = t & 63;
    const int hws = hw0 + spx;
    const int hh = hws / WW, wwp = hws % WW;

    auto STAGE = [&](int q, int buf) {
        const int dy = q / 3 - 1, dx = q % 3 - 1;
        const int y = hh + dy, xx = wwp + dx;
        const bool valid = ((unsigned)y < 80u) && ((unsigned)xx < 80u);
        const ushort_t* src = xm_bf + ((size_t)bb * HW + y * WW + xx) * 128 + wave * 32;
#pragma unroll
        for (int s = 0; s < 4; ++s) {
            uint4 v = make_uint4(0u, 0u, 0u, 0u);
            if (valid) v = *reinterpret_cast<const uint4*>(src + s * 8);
            const int cslot = wave * 4 + s;
            *reinterpret_cast<uint4*>(&A[buf][spx * 128 + ((cslot ^ (spx & 7)) << 3)]) = v;
        }
    };

    const int q4 = lane >> 4, ln = lane & 15;
    f32x4 acc[2] = {};

    auto GEMM = [&](int q, int buf) {
#pragma unroll
        for (int ks = 0; ks < 4; ++ks) {
            const int px = wave * 16 + ln;
            const int elem = px * 128 + (((ks * 4 + q4) ^ (px & 7)) << 3);
            const short8 a = *reinterpret_cast<const short8*>(&A[buf][elem]);
#pragma unroll
            for (int nf = 0; nf < 2; ++nf) {
                const int chunk = nf * 36 + q * 4 + ks;
                const short8 b = *reinterpret_cast<const short8*>(WoB + chunk * 512 + lane * 8);
                acc[nf] = __builtin_amdgcn_mfma_f32_16x16x32_bf16(a, b, acc[nf], 0, 0, 0);
            }
        }
    };

    STAGE(0, 0);
    __syncthreads();
    for (int q = 0; q < 9; ++q) {
        if (q < 8) STAGE(q + 1, (q + 1) & 1);
        GEMM(q, q & 1);
        __syncthreads();
    }

#pragma unroll
    for (int nf = 0; nf < 2; ++nf)
#pragma unroll
        for (int r = 0; r < 4; ++r) {
            const int o = nf * 16 + ln;
            const int px = wave * 16 + q4 * 4 + r;
            T[o * 64 + px] = acc[nf][r];
        }
    __syncthreads();
    for (int i = t; i < 27 * 64; i += 256) {
        const int o = i >> 6, px = i & 63;
        om[((size_t)bb * 27 + o) * HW + hw0 + px] = T[i] + obias[o];
    }
}

// ---------------------------------------------------------------------------
// k3: deform-sample (channel-last bf16 gather) -> LDS -> MFMA -> BN+SiLU
// 512 thr (8 waves), 64 px x 256 o per block.
// ---------------------------------------------------------------------------
__global__ __launch_bounds__(512) void k3_dcn(
    const ushort_t* __restrict__ xm_bf, const float* __restrict__ om,
    const ushort_t* __restrict__ WdB,
    const float* __restrict__ g, const float* __restrict__ be,
    const float* __restrict__ mu, const float* __restrict__ va,
    float* __restrict__ out)
{
    __shared__ __align__(16) ushort_t S[2][64 * 128];  // 2 x 16 KB
    __shared__ __align__(16) float4 geoW[9][64];       // 9 KB
    __shared__ __align__(16) int4   geoI[9][64];       // 9 KB

    const int t    = threadIdx.x;
    const int lane = t & 63;
    const int wave = t >> 6;
    const int p0   = blockIdx.x * 64;
    const int bb   = p0 / HW;
    const int hw0  = p0 % HW;

    for (int it = t; it < 576; it += 512) {
        const int tap = it >> 6, px = it & 63;
        const int hw = hw0 + px;
        const int h = hw / WW, w = hw % WW;
        const float* ob = om + (size_t)bb * 27 * HW + hw;
        const float oy = ob[(2 * tap) * HW];
        const float ox = ob[(2 * tap + 1) * HW];
        const float mk = sigmoidf_(ob[(18 + tap) * HW]);
        float py  = (float)(h - 1 + tap / 3) + oy;
        float pxf = (float)(w - 1 + tap % 3) + ox;
        py  = fminf(fmaxf(py, -1000.f), 1000.f);
        pxf = fminf(fmaxf(pxf, -1000.f), 1000.f);
        const float fy = floorf(py), fx = floorf(pxf);
        const int y0 = (int)fy, x0 = (int)fx, y1 = y0 + 1, x1 = x0 + 1;
        const float wy = py - fy, wx = pxf - fx;
        const float vy0 = ((unsigned)y0 < 80u) ? 1.f : 0.f;
        const float vy1 = ((unsigned)y1 < 80u) ? 1.f : 0.f;
        const float vx0 = ((unsigned)x0 < 80u) ? 1.f : 0.f;
        const float vx1 = ((unsigned)x1 < 80u) ? 1.f : 0.f;
        float4 wv;
        wv.x = (1.f - wy) * (1.f - wx) * vy0 * vx0 * mk;
        wv.y = (1.f - wy) * wx * vy0 * vx1 * mk;
        wv.z = wy * (1.f - wx) * vy1 * vx0 * mk;
        wv.w = wy * wx * vy1 * vx1 * mk;
        const int cy0 = min(max(y0, 0), 79), cy1 = min(max(y1, 0), 79);
        const int cx0 = min(max(x0, 0), 79), cx1 = min(max(x1, 0), 79);
        int4 iv;
        iv.x = cy0 * WW + cx0; iv.y = cy0 * WW + cx1;
        iv.z = cy1 * WW + cx0; iv.w = cy1 * WW + cx1;
        geoW[tap][px] = wv;
        geoI[tap][px] = iv;
    }
    __syncthreads();

    const ushort_t* xb = xm_bf + (size_t)bb * HW * 128;

    const int spx = t >> 3;
    const int scg = t & 7;

    auto SAMPLE = [&](int tap, int bufIdx) {
        const float4 wv = geoW[tap][spx];
        const int4  iv = geoI[tap][spx];
        const uint4* c00 = reinterpret_cast<const uint4*>(xb + (size_t)iv.x * 128 + scg * 16);
        const uint4* c01 = reinterpret_cast<const uint4*>(xb + (size_t)iv.y * 128 + scg * 16);
        const uint4* c10 = reinterpret_cast<const uint4*>(xb + (size_t)iv.z * 128 + scg * 16);
        const uint4* c11 = reinterpret_cast<const uint4*>(xb + (size_t)iv.w * 128 + scg * 16);
#pragma unroll
        for (int half = 0; half < 2; ++half) {
            const uint4 a = c00[half], b = c01[half], c = c10[half], d = c11[half];
            const unsigned* ap = (const unsigned*)&a;
            const unsigned* bp = (const unsigned*)&b;
            const unsigned* cp = (const unsigned*)&c;
            const unsigned* dp = (const unsigned*)&d;
            unsigned pk[4];
#pragma unroll
            for (int u = 0; u < 4; ++u) {
                const float alo = __uint_as_float(ap[u] << 16), ahi = __uint_as_float(ap[u] & 0xFFFF0000u);
                const float blo = __uint_as_float(bp[u] << 16), bhi = __uint_as_float(bp[u] & 0xFFFF0000u);
                const float clo = __uint_as_float(cp[u] << 16), chi = __uint_as_float(cp[u] & 0xFFFF0000u);
                const float dlo = __uint_as_float(dp[u] << 16), dhi = __uint_as_float(dp[u] & 0xFFFF0000u);
                const float slo = wv.x * alo + wv.y * blo + wv.z * clo + wv.w * dlo;
                const float shi = wv.x * ahi + wv.y * bhi + wv.z * chi + wv.w * dhi;
                pk[u] = (unsigned)f2bf(slo) | ((unsigned)f2bf(shi) << 16);
            }
            const int cslot = scg * 2 + half;
            const int elem  = spx * 128 + ((cslot ^ (spx & 7)) << 3);
            *reinterpret_cast<uint4*>(&S[bufIdx][elem]) =
                make_uint4(pk[0], pk[1], pk[2], pk[3]);
        }
    };

    const int wM = wave >> 2, wN = wave & 3;
    const int q = lane >> 4, ln = lane & 15;
    f32x4 acc[2][4] = {};

    auto GEMM = [&](int tap, int bufIdx) {
#pragma unroll
        for (int ks = 0; ks < 4; ++ks) {
            short8 a0, a1;
            {
                const int px = wM * 32 + ln;
                const int elem = px * 128 + (((ks * 4 + q) ^ (px & 7)) << 3);
                a0 = *reinterpret_cast<const short8*>(&S[bufIdx][elem]);
            }
            {
                const int px = wM * 32 + 16 + ln;
                const int elem = px * 128 + (((ks * 4 + q) ^ (px & 7)) << 3);
                a1 = *reinterpret_cast<const short8*>(&S[bufIdx][elem]);
            }
#pragma unroll
            for (int nt = 0; nt < 4; ++nt) {
                const int ot = wN * 4 + nt;
                const int chunk = ot * 36 + tap * 4 + ks;
                const short8 b = *reinterpret_cast<const short8*>(WdB + chunk * 512 + lane * 8);
                acc[0][nt] = __builtin_amdgcn_mfma_f32_16x16x32_bf16(a0, b, acc[0][nt], 0, 0, 0);
                acc[1][nt] = __builtin_amdgcn_mfma_f32_16x16x32_bf16(a1, b, acc[1][nt], 0, 0, 0);
            }
        }
    };

    SAMPLE(0, 0);
    __syncthreads();
    for (int tap = 0; tap < 9; ++tap) {
        if (tap < 8) SAMPLE(tap + 1, (tap + 1) & 1);
        GEMM(tap, tap & 1);
        __syncthreads();
    }

    float sc[4], sh[4];
#pragma unroll
    for (int nt = 0; nt < 4; ++nt) {
        const int o = wN * 64 + nt * 16 + ln;
        sc[nt] = g[o] * rsqrtf(va[o] + 1e-5f);
        sh[nt] = be[o] - mu[o] * sc[nt];
    }
#pragma unroll
    for (int mt = 0; mt < 2; ++mt)
#pragma unroll
        for (int nt = 0; nt < 4; ++nt) {
            const int o = wN * 64 + nt * 16 + ln;
            float* obase = out + (size_t)bb * 256 * HW + (size_t)o * HW;
            float4 st;
            st.x = siluf_(acc[mt][nt][0] * sc[nt] + sh[nt]);
            st.y = siluf_(acc[mt][nt][1] * sc[nt] + sh[nt]);
            st.z = siluf_(acc[mt][nt][2] * sc[nt] + sh[nt]);
            st.w = siluf_(acc[mt][nt][3] * sc[nt] + sh[nt]);
            *reinterpret_cast<float4*>(obase + hw0 + wM * 32 + mt * 16 + q * 4) = st;
        }
}

// ---------------------------------------------------------------------------
extern "C" void kernel_launch(void* const* d_in, const int* in_sizes, int n_in,
                              void* d_out, int out_size, void* d_ws, size_t ws_size,
                              hipStream_t stream)
{
    const float* x        = (const float*)d_in[0];
    const float* reduce_w = (const float*)d_in[1];
    const float* rg       = (const float*)d_in[2];
    const float* rb       = (const float*)d_in[3];
    const float* rm       = (const float*)d_in[4];
    const float* rv       = (const float*)d_in[5];
    const float* off_w    = (const float*)d_in[6];
    const float* off_b    = (const float*)d_in[7];
    const float* dcn_w    = (const float*)d_in[8];
    const float* dg       = (const float*)d_in[9];
    const float* db       = (const float*)d_in[10];
    const float* dm       = (const float*)d_in[11];
    const float* dv       = (const float*)d_in[12];

    float* ws  = (float*)d_ws;
    ushort_t* xm_bf = (ushort_t*)ws;                 // 6,553,600 bf16
    float* om   = ws + 3276800;                      // 1,382,400 f
    ushort_t* WB   = (ushort_t*)(om + 1382400);      // 65,536 bf16
    ushort_t* WoB  = WB + 65536;                     // 36,864 bf16
    ushort_t* WdB  = WoB + 36864;                    // 294,912 bf16
    float* scr = (float*)(WdB + 294912);             // 128 f
    float* shr = scr + 128;                          // 128 f

    k0_prep<<<dim3(1552), dim3(256), 0, stream>>>(reduce_w, off_w, dcn_w,
                                                  rg, rb, rm, rv,
                                                  WB, WoB, WdB, scr, shr);
    k1_reduce<<<dim3(800), dim3(256), 0, stream>>>(x, WB, scr, shr, xm_bf);
    k2_off<<<dim3(800), dim3(256), 0, stream>>>(xm_bf, WoB, off_b, om);
    k3_dcn<<<dim3(800), dim3(512), 0, stream>>>(xm_bf, om, WdB, dg, db, dm, dv, (float*)d_out);
}

// Round 9
// 173.966 us; speedup vs baseline: 4.6923x; 1.1204x over previous
//
#include <hip/hip_runtime.h>

constexpr int HW  = 6400;   // 80*80
constexpr int WW  = 80;

typedef __attribute__((ext_vector_type(8))) short short8;   // 8 bf16 = 4 VGPR
typedef __attribute__((ext_vector_type(4))) float f32x4;
typedef unsigned short ushort_t;

__device__ __forceinline__ float sigmoidf_(float x) { return 1.f / (1.f + __expf(-x)); }
__device__ __forceinline__ float siluf_(float y) { return y / (1.f + __expf(-y)); }
__device__ __forceinline__ ushort_t f2bf(float f) {   // RNE f32->bf16
    unsigned u = __float_as_uint(f);
    u += 0x7FFFu + ((u >> 16) & 1u);
    return (ushort_t)(u >> 16);
}
__device__ __forceinline__ float bf2f(ushort_t h) {
    return __uint_as_float(((unsigned)h) << 16);
}

// ---------------------------------------------------------------------------
// k0: weight prep (bf16 MFMA fragment layouts)
//  WB:  reduce_w frags. chunk = nt*16+kks (nt 0..7, kks 0..15);
//       entry lane*8+e: o = nt*16+(lane&15), kk = kks*32+(lane>>4)*8+e (kk = cs)
//  WoB: off_w frags, chunk = nf*36+ksg (nf 0..1), K = q*128+c
//  WdB: dcn_w frags, chunk = ot*36+ksg (ot 0..15), K = tap*128+c
//  scr/shr: reduce-BN scale/shift fp32
// ---------------------------------------------------------------------------
__global__ __launch_bounds__(256) void k0_prep(
    const float* __restrict__ rw, const float* __restrict__ ow,
    const float* __restrict__ dw,
    const float* __restrict__ rg, const float* __restrict__ rb,
    const float* __restrict__ rm, const float* __restrict__ rv,
    ushort_t* __restrict__ WB,
    ushort_t* __restrict__ WoB, ushort_t* __restrict__ WdB,
    float* __restrict__ scr, float* __restrict__ shr)
{
    const int i = blockIdx.x * 256 + threadIdx.x;
    if (blockIdx.x == 0 && threadIdx.x < 128) {
        const int m = threadIdx.x;
        const float sc = rg[m] * rsqrtf(rv[m] + 1e-5f);
        scr[m] = sc;
        shr[m] = rb[m] - rm[m] * sc;
    }
    if (i < 65536) {                       // WB: 128 chunks * 512
        const int e = i & 7;
        const int lane = (i >> 3) & 63;
        const int chunkW = i >> 9;         // 0..127
        const int nt = chunkW >> 4, kks = chunkW & 15;
        const int kk = kks * 32 + ((lane >> 4) << 3) + e;   // cs 0..511
        const int o = (nt << 4) + (lane & 15);              // out ch 0..127
        WB[i] = f2bf(rw[o * 512 + kk]);
    }
    const int j = i - 65536;
    if (j >= 0 && j < 36864) {             // WoB: 2*36*512
        const int e = j & 7;
        const int lane = (j >> 3) & 63;
        const int chunk = j >> 9;
        const int nf = chunk / 36, ksg = chunk % 36;
        const int kk = ksg * 32 + ((lane >> 4) << 3) + e;
        const int q = kk >> 7, c = kk & 127;
        const int o = (nf << 4) + (lane & 15);
        WoB[j] = (o < 27) ? f2bf(ow[o * 1152 + c * 9 + q]) : (ushort_t)0;
    }
    const int l = j - 36864;
    if (l >= 0 && l < 294912) {            // WdB: 16*36*512
        const int e = l & 7;
        const int lane = (l >> 3) & 63;
        const int chunk = l >> 9;
        const int ot = chunk / 36, ksg = chunk % 36;
        const int kk = ksg * 32 + ((lane >> 4) << 3) + e;
        const int tap = kk >> 7, c = kk & 127;
        const int o = (ot << 4) + (lane & 15);
        WdB[l] = f2bf(dw[o * 1152 + c * 9 + tap]);
    }
}

// ---------------------------------------------------------------------------
// k1 v3: space-to-depth + 1x1 conv as bf16 MFMA, NO LDS.
// ---------------------------------------------------------------------------
__global__ __launch_bounds__(256) void k1_reduce(
    const float* __restrict__ x,
    const ushort_t* __restrict__ WB,
    const float* __restrict__ scr, const float* __restrict__ shr,
    ushort_t* __restrict__ xm_bf)
{
    const int t    = threadIdx.x;
    const int lane = t & 63;
    const int wave = t >> 6;
    const int q = lane >> 4, ln = lane & 15;
    const int p0 = blockIdx.x * 64;
    const int bb = p0 / HW;
    const int px = wave * 16 + ln;
    const int hw = (p0 % HW) + px;
    const int h = hw / WW, w = hw % WW;
    const float* xb = x + (size_t)bb * 128 * 25600 + (2 * h) * 160 + 2 * w;

    f32x4 acc[8] = {};

#pragma unroll 4
    for (int kks = 0; kks < 16; ++kks) {
        const int c0 = kks * 8 + q * 2;       // 2 channels per fragment
        const float* pc0 = xb + (size_t)c0 * 25600;
        const float* pc1 = pc0 + 25600;
        const float2 a0 = *reinterpret_cast<const float2*>(pc0);
        const float2 a1 = *reinterpret_cast<const float2*>(pc0 + 160);
        const float2 b0 = *reinterpret_cast<const float2*>(pc1);
        const float2 b1 = *reinterpret_cast<const float2*>(pc1 + 160);
        short8 p;
        p[0] = (short)f2bf(a0.x); p[1] = (short)f2bf(a0.y);
        p[2] = (short)f2bf(a1.x); p[3] = (short)f2bf(a1.y);
        p[4] = (short)f2bf(b0.x); p[5] = (short)f2bf(b0.y);
        p[6] = (short)f2bf(b1.x); p[7] = (short)f2bf(b1.y);
#pragma unroll
        for (int nt = 0; nt < 8; ++nt) {
            const short8 wf = *reinterpret_cast<const short8*>(WB + ((nt << 4) + kks) * 512 + lane * 8);
            acc[nt] = __builtin_amdgcn_mfma_f32_16x16x32_bf16(wf, p, acc[nt], 0, 0, 0);
        }
    }

    const int pi = p0 + px;
    ushort_t* op = xm_bf + (size_t)pi * 128;
#pragma unroll
    for (int nt = 0; nt < 8; ++nt) {
        const int ob = nt * 16 + q * 4;
        const float4 s4 = *reinterpret_cast<const float4*>(scr + ob);
        const float4 b4 = *reinterpret_cast<const float4*>(shr + ob);
        const float y0 = siluf_(acc[nt][0] * s4.x + b4.x);
        const float y1 = siluf_(acc[nt][1] * s4.y + b4.y);
        const float y2 = siluf_(acc[nt][2] * s4.z + b4.z);
        const float y3 = siluf_(acc[nt][3] * s4.w + b4.w);
        *reinterpret_cast<uint2*>(op + ob) =
            make_uint2(f2bf(y0) | ((unsigned)f2bf(y1) << 16),
                       f2bf(y2) | ((unsigned)f2bf(y3) << 16));
    }
}

// ---------------------------------------------------------------------------
// k2: 3x3 conv (128->27) + bias via MFMA. M=64px/block, K=1152, N=32.
// ---------------------------------------------------------------------------
__global__ __launch_bounds__(256) void k2_off(
    const ushort_t* __restrict__ xm_bf, const ushort_t* __restrict__ WoB,
    const float* __restrict__ obias, float* __restrict__ om)
{
    __shared__ __align__(16) ushort_t A[2][64 * 128];   // 2 x 16 KB
    __shared__ __align__(16) float T[32 * 64];          // 8 KB

    const int t = threadIdx.x;
    const int lane = t & 63;
    const int wave = t >> 6;
    const int p0 = blockIdx.x * 64;
    const int bb = p0 / HW;
    const int hw0 = p0 % HW;

    const int spx = t & 63;
    const int hws = hw0 + spx;
    const int hh = hws / WW, wwp = hws % WW;

    auto STAGE = [&](int q, int buf) {
        const int dy = q / 3 - 1, dx = q % 3 - 1;
        const int y = hh + dy, xx = wwp + dx;
        const bool valid = ((unsigned)y < 80u) && ((unsigned)xx < 80u);
        const ushort_t* src = xm_bf + ((size_t)bb * HW + y * WW + xx) * 128 + wave * 32;
#pragma unroll
        for (int s = 0; s < 4; ++s) {
            uint4 v = make_uint4(0u, 0u, 0u, 0u);
            if (valid) v = *reinterpret_cast<const uint4*>(src + s * 8);
            const int cslot = wave * 4 + s;
            *reinterpret_cast<uint4*>(&A[buf][spx * 128 + ((cslot ^ (spx & 7)) << 3)]) = v;
        }
    };

    const int q4 = lane >> 4, ln = lane & 15;
    f32x4 acc[2] = {};

    auto GEMM = [&](int q, int buf) {
#pragma unroll
        for (int ks = 0; ks < 4; ++ks) {
            const int px = wave * 16 + ln;
            const int elem = px * 128 + (((ks * 4 + q4) ^ (px & 7)) << 3);
            const short8 a = *reinterpret_cast<const short8*>(&A[buf][elem]);
#pragma unroll
            for (int nf = 0; nf < 2; ++nf) {
                const int chunk = nf * 36 + q * 4 + ks;
                const short8 b = *reinterpret_cast<const short8*>(WoB + chunk * 512 + lane * 8);
                acc[nf] = __builtin_amdgcn_mfma_f32_16x16x32_bf16(a, b, acc[nf], 0, 0, 0);
            }
        }
    };

    STAGE(0, 0);
    __syncthreads();
    for (int q = 0; q < 9; ++q) {
        if (q < 8) STAGE(q + 1, (q + 1) & 1);
        GEMM(q, q & 1);
        __syncthreads();
    }

#pragma unroll
    for (int nf = 0; nf < 2; ++nf)
#pragma unroll
        for (int r = 0; r < 4; ++r) {
            const int o = nf * 16 + ln;
            const int px = wave * 16 + q4 * 4 + r;
            T[o * 64 + px] = acc[nf][r];
        }
    __syncthreads();
    for (int i = t; i < 27 * 64; i += 256) {
        const int o = i >> 6, px = i & 63;
        om[((size_t)bb * 27 + o) * HW + hw0 + px] = T[i] + obias[o];
    }
}

// ---------------------------------------------------------------------------
// k3 v4: deform-sample with T14 async split (issue-early / blend-late).
// Per tap: ISSUE(t+1) global loads -> regs; GEMM(t) MFMAs; then wait+BLEND+
// WRITE(t+1) into the other LDS buffer; one barrier per tap.
// 512 thr (8 waves), 64 px x 256 o per block.
// ---------------------------------------------------------------------------
__global__ __launch_bounds__(512) void k3_dcn(
    const ushort_t* __restrict__ xm_bf, const float* __restrict__ om,
    const ushort_t* __restrict__ WdB,
    const float* __restrict__ g, const float* __restrict__ be,
    const float* __restrict__ mu, const float* __restrict__ va,
    float* __restrict__ out)
{
    __shared__ __align__(16) ushort_t S[2][64 * 128];  // 2 x 16 KB
    __shared__ __align__(16) float4 geoW[9][64];       // 9 KB
    __shared__ __align__(16) int4   geoI[9][64];       // 9 KB

    const int t    = threadIdx.x;
    const int lane = t & 63;
    const int wave = t >> 6;
    const int p0   = blockIdx.x * 64;
    const int bb   = p0 / HW;
    const int hw0  = p0 % HW;

    for (int it = t; it < 576; it += 512) {
        const int tap = it >> 6, px = it & 63;
        const int hw = hw0 + px;
        const int h = hw / WW, w = hw % WW;
        const float* ob = om + (size_t)bb * 27 * HW + hw;
        const float oy = ob[(2 * tap) * HW];
        const float ox = ob[(2 * tap + 1) * HW];
        const float mk = sigmoidf_(ob[(18 + tap) * HW]);
        float py  = (float)(h - 1 + tap / 3) + oy;
        float pxf = (float)(w - 1 + tap % 3) + ox;
        py  = fminf(fmaxf(py, -1000.f), 1000.f);
        pxf = fminf(fmaxf(pxf, -1000.f), 1000.f);
        const float fy = floorf(py), fx = floorf(pxf);
        const int y0 = (int)fy, x0 = (int)fx, y1 = y0 + 1, x1 = x0 + 1;
        const float wy = py - fy, wx = pxf - fx;
        const float vy0 = ((unsigned)y0 < 80u) ? 1.f : 0.f;
        const float vy1 = ((unsigned)y1 < 80u) ? 1.f : 0.f;
        const float vx0 = ((unsigned)x0 < 80u) ? 1.f : 0.f;
        const float vx1 = ((unsigned)x1 < 80u) ? 1.f : 0.f;
        float4 wv;
        wv.x = (1.f - wy) * (1.f - wx) * vy0 * vx0 * mk;
        wv.y = (1.f - wy) * wx * vy0 * vx1 * mk;
        wv.z = wy * (1.f - wx) * vy1 * vx0 * mk;
        wv.w = wy * wx * vy1 * vx1 * mk;
        const int cy0 = min(max(y0, 0), 79), cy1 = min(max(y1, 0), 79);
        const int cx0 = min(max(x0, 0), 79), cx1 = min(max(x1, 0), 79);
        int4 iv;
        iv.x = cy0 * WW + cx0; iv.y = cy0 * WW + cx1;
        iv.z = cy1 * WW + cx0; iv.w = cy1 * WW + cx1;
        geoW[tap][px] = wv;
        geoI[tap][px] = iv;
    }
    __syncthreads();

    const ushort_t* xb = xm_bf + (size_t)bb * HW * 128;

    const int spx = t >> 3;
    const int scg = t & 7;

    // prefetched corner data: [corner 0..3][half 0..1]
    uint4 pr[8];

    auto ISSUE = [&](int tap) {
        const int4 iv = geoI[tap][spx];
        const uint4* c00 = reinterpret_cast<const uint4*>(xb + (size_t)iv.x * 128 + scg * 16);
        const uint4* c01 = reinterpret_cast<const uint4*>(xb + (size_t)iv.y * 128 + scg * 16);
        const uint4* c10 = reinterpret_cast<const uint4*>(xb + (size_t)iv.z * 128 + scg * 16);
        const uint4* c11 = reinterpret_cast<const uint4*>(xb + (size_t)iv.w * 128 + scg * 16);
        pr[0] = c00[0]; pr[1] = c00[1];
        pr[2] = c01[0]; pr[3] = c01[1];
        pr[4] = c10[0]; pr[5] = c10[1];
        pr[6] = c11[0]; pr[7] = c11[1];
    };

    auto BLEND_WRITE = [&](int tap, int bufIdx) {
        const float4 wv = geoW[tap][spx];
#pragma unroll
        for (int half = 0; half < 2; ++half) {
            const unsigned* ap = (const unsigned*)&pr[0 + half];
            const unsigned* bp = (const unsigned*)&pr[2 + half];
            const unsigned* cp = (const unsigned*)&pr[4 + half];
            const unsigned* dp = (const unsigned*)&pr[6 + half];
            unsigned pk[4];
#pragma unroll
            for (int u = 0; u < 4; ++u) {
                const float alo = __uint_as_float(ap[u] << 16), ahi = __uint_as_float(ap[u] & 0xFFFF0000u);
                const float blo = __uint_as_float(bp[u] << 16), bhi = __uint_as_float(bp[u] & 0xFFFF0000u);
                const float clo = __uint_as_float(cp[u] << 16), chi = __uint_as_float(cp[u] & 0xFFFF0000u);
                const float dlo = __uint_as_float(dp[u] << 16), dhi = __uint_as_float(dp[u] & 0xFFFF0000u);
                const float slo = wv.x * alo + wv.y * blo + wv.z * clo + wv.w * dlo;
                const float shi = wv.x * ahi + wv.y * bhi + wv.z * chi + wv.w * dhi;
                pk[u] = (unsigned)f2bf(slo) | ((unsigned)f2bf(shi) << 16);
            }
            const int cslot = scg * 2 + half;
            const int elem  = spx * 128 + ((cslot ^ (spx & 7)) << 3);
            *reinterpret_cast<uint4*>(&S[bufIdx][elem]) =
                make_uint4(pk[0], pk[1], pk[2], pk[3]);
        }
    };

    const int wM = wave >> 2, wN = wave & 3;
    const int q = lane >> 4, ln = lane & 15;
    f32x4 acc[2][4] = {};

    auto GEMM = [&](int tap, int bufIdx) {
#pragma unroll
        for (int ks = 0; ks < 4; ++ks) {
            short8 a0, a1;
            {
                const int px = wM * 32 + ln;
                const int elem = px * 128 + (((ks * 4 + q) ^ (px & 7)) << 3);
                a0 = *reinterpret_cast<const short8*>(&S[bufIdx][elem]);
            }
            {
                const int px = wM * 32 + 16 + ln;
                const int elem = px * 128 + (((ks * 4 + q) ^ (px & 7)) << 3);
                a1 = *reinterpret_cast<const short8*>(&S[bufIdx][elem]);
            }
#pragma unroll
            for (int nt = 0; nt < 4; ++nt) {
                const int ot = wN * 4 + nt;
                const int chunk = ot * 36 + tap * 4 + ks;
                const short8 b = *reinterpret_cast<const short8*>(WdB + chunk * 512 + lane * 8);
                acc[0][nt] = __builtin_amdgcn_mfma_f32_16x16x32_bf16(a0, b, acc[0][nt], 0, 0, 0);
                acc[1][nt] = __builtin_amdgcn_mfma_f32_16x16x32_bf16(a1, b, acc[1][nt], 0, 0, 0);
            }
        }
    };

    // prologue: fill buf0 for tap 0
    ISSUE(0);
    BLEND_WRITE(0, 0);
    __syncthreads();

    for (int tap = 0; tap < 9; ++tap) {
        if (tap < 8) ISSUE(tap + 1);           // loads in flight across GEMM
        GEMM(tap, tap & 1);
        if (tap < 8) BLEND_WRITE(tap + 1, (tap + 1) & 1);
        __syncthreads();
    }

    float sc[4], sh[4];
#pragma unroll
    for (int nt = 0; nt < 4; ++nt) {
        const int o = wN * 64 + nt * 16 + ln;
        sc[nt] = g[o] * rsqrtf(va[o] + 1e-5f);
        sh[nt] = be[o] - mu[o] * sc[nt];
    }
#pragma unroll
    for (int mt = 0; mt < 2; ++mt)
#pragma unroll
        for (int nt = 0; nt < 4; ++nt) {
            const int o = wN * 64 + nt * 16 + ln;
            float* obase = out + (size_t)bb * 256 * HW + (size_t)o * HW;
            float4 st;
            st.x = siluf_(acc[mt][nt][0] * sc[nt] + sh[nt]);
            st.y = siluf_(acc[mt][nt][1] * sc[nt] + sh[nt]);
            st.z = siluf_(acc[mt][nt][2] * sc[nt] + sh[nt]);
            st.w = siluf_(acc[mt][nt][3] * sc[nt] + sh[nt]);
            *reinterpret_cast<float4*>(obase + hw0 + wM * 32 + mt * 16 + q * 4) = st;
        }
}

// ---------------------------------------------------------------------------
extern "C" void kernel_launch(void* const* d_in, const int* in_sizes, int n_in,
                              void* d_out, int out_size, void* d_ws, size_t ws_size,
                              hipStream_t stream)
{
    const float* x        = (const float*)d_in[0];
    const float* reduce_w = (const float*)d_in[1];
    const float* rg       = (const float*)d_in[2];
    const float* rb       = (const float*)d_in[3];
    const float* rm       = (const float*)d_in[4];
    const float* rv       = (const float*)d_in[5];
    const float* off_w    = (const float*)d_in[6];
    const float* off_b    = (const float*)d_in[7];
    const float* dcn_w    = (const float*)d_in[8];
    const float* dg       = (const float*)d_in[9];
    const float* db       = (const float*)d_in[10];
    const float* dm       = (const float*)d_in[11];
    const float* dv       = (const float*)d_in[12];

    float* ws  = (float*)d_ws;
    ushort_t* xm_bf = (ushort_t*)ws;                 // 6,553,600 bf16
    float* om   = ws + 3276800;                      // 1,382,400 f
    ushort_t* WB   = (ushort_t*)(om + 1382400);      // 65,536 bf16
    ushort_t* WoB  = WB + 65536;                     // 36,864 bf16
    ushort_t* WdB  = WoB + 36864;                    // 294,912 bf16
    float* scr = (float*)(WdB + 294912);             // 128 f
    float* shr = scr + 128;                          // 128 f

    k0_prep<<<dim3(1552), dim3(256), 0, stream>>>(reduce_w, off_w, dcn_w,
                                                  rg, rb, rm, rv,
                                                  WB, WoB, WdB, scr, shr);
    k1_reduce<<<dim3(800), dim3(256), 0, stream>>>(x, WB, scr, shr, xm_bf);
    k2_off<<<dim3(800), dim3(256), 0, stream>>>(xm_bf, WoB, off_b, om);
    k3_dcn<<<dim3(800), dim3(512), 0, stream>>>(xm_bf, om, WdB, dg, db, dm, dv, (float*)d_out);
}